// Round 8
// baseline (526.335 us; speedup 1.0000x reference)
//
#include <hip/hip_runtime.h>
#include <stdint.h>

typedef float  f32x4 __attribute__((ext_vector_type(4)));
typedef short  s16x8 __attribute__((ext_vector_type(8)));
typedef _Float16 h16x8 __attribute__((ext_vector_type(8)));
typedef unsigned short u16x4 __attribute__((ext_vector_type(4)));

#define DEV __device__ __forceinline__

DEV unsigned short f2bf(float f) {
  union { float f; unsigned int u; } v; v.f = f;
  unsigned int u = v.u;
  return (unsigned short)((u + 0x7fffu + ((u >> 16) & 1u)) >> 16);
}

typedef const __attribute__((address_space(1))) void* as1cvp;
typedef __attribute__((address_space(3))) void* as3vp;
DEV void gload16(const void* g, void* l) {
  __builtin_amdgcn_global_load_lds((as1cvp)g, (as3vp)l, 16, 0, 0);
}

// ---------------- pack kernels (memory-bound) ----------------

// fp32 -> fp16 flat (total8 = count/8)
__global__ __launch_bounds__(256) void pack_f16(const float* __restrict__ in,
                                                unsigned short* __restrict__ out, long total8)
{
  for (long t = (long)blockIdx.x * 256 + threadIdx.x; t < total8;
       t += (long)gridDim.x * 256) {
    const float* src = in + t * 8;
    f32x4 x0 = *(const f32x4*)src;
    f32x4 x1 = *(const f32x4*)(src + 4);
    s16x8 h8;
    #pragma unroll
    for (int e = 0; e < 4; ++e) {
      h8[e]     = (short)__builtin_bit_cast(unsigned short, (_Float16)x0[e]);
      h8[e + 4] = (short)__builtin_bit_cast(unsigned short, (_Float16)x1[e]);
    }
    *(s16x8*)(out + t * 8) = h8;
  }
}

// fp32 -> bf16 flat
__global__ __launch_bounds__(256) void pack_bf16(const float* __restrict__ in,
                                                 unsigned short* __restrict__ out, long total8)
{
  for (long t = (long)blockIdx.x * 256 + threadIdx.x; t < total8;
       t += (long)gridDim.x * 256) {
    const float* src = in + t * 8;
    f32x4 x0 = *(const f32x4*)src;
    f32x4 x1 = *(const f32x4*)(src + 4);
    s16x8 h8;
    #pragma unroll
    for (int e = 0; e < 4; ++e) {
      h8[e]     = (short)f2bf(x0[e]);
      h8[e + 4] = (short)f2bf(x1[e]);
    }
    *(s16x8*)(out + t * 8) = h8;
  }
}

// ---------------- 256x256 8-phase NT GEMM (bf16 or fp16) ----------------
// Grid (32, 8): bx -> M-block via XCD remap (xcd = bx&7 owns M-panels
// (bx&7)*4..+3), by -> N-block. C[m,n] = sum_k A[m,k]*B[n,k] + bias[n].
// DT 0: bf16 MFMA; DT 1: fp16 MFMA (same fragment geometry). K = 2048.
// OM 0: fp32 row-major (ldc 2048); OM 1: bf16 scatter vT[((b*8+h)*256+i)*256+s].
// LDS swizzle: read u ^= ((u>>8)&1)<<5 (bank-bit4 by row-bit2); write side via
// source chunk-col ^ ((tid>>5)&1)<<2 (same involution, LDS dest linear).
template<int DT>
DEV f32x4 mfma16(s16x8 a, s16x8 b, f32x4 c) {
  if constexpr (DT == 0)
    return __builtin_amdgcn_mfma_f32_16x16x32_bf16(a, b, c, 0, 0, 0);
  else
    return __builtin_amdgcn_mfma_f32_16x16x32_f16(
        __builtin_bit_cast(h16x8, a), __builtin_bit_cast(h16x8, b), c, 0, 0, 0);
}

template<int DT, int OM>
__global__ __launch_bounds__(512, 2)
void gemm8p(const unsigned short* __restrict__ Ap, const unsigned short* __restrict__ Bp,
            const float* __restrict__ bias, void* __restrict__ Cp)
{
  constexpr int LD  = 2048;
  constexpr int LDC = 2048;
  constexpr int NT  = 32;    // K-tiles of 64
  constexpr int NI  = NT / 2;

  __shared__ __align__(16) unsigned short lds[65536];  // 128 KB

  const int tid  = threadIdx.x;
  const int lane = tid & 63;
  const int wid  = tid >> 6;
  const int wm   = wid >> 2;        // 0..1
  const int wn   = wid & 3;         // 0..3
  const int fr   = lane & 15;
  const int ko   = (lane >> 4) * 8;

  const int bx = blockIdx.x;                       // 0..31
  const int m0 = (((bx & 7) << 2) + (bx >> 3)) * 256;
  const int n0 = blockIdx.y * 256;

  // staging: row sr = tid>>3, chunk-col (tid&7) with bank-swizzle bit2 flip
  const int sr  = tid >> 3;
  const int scc = (((tid & 7) ^ (((tid >> 5) & 1) << 2)) << 3); // src col elems

  auto sA = [&](int d, int u, int col) {
    const unsigned short* s0 = Ap + (long)(m0 + u * 64 + sr) * LD + col + scc;
    const int lb = d * 32768 + u * 4096 + (wid << 9);
    gload16(s0, lds + lb);
    gload16(s0 + 128 * LD, lds + lb + 8192);
  };
  auto sB = [&](int d, int h, int col) {
    const unsigned short* s0 = Bp + (long)(n0 + h * 128 + sr) * LD + col + scc;
    const int lb = d * 32768 + 16384 + h * 8192 + (wid << 9);
    gload16(s0, lds + lb);
    gload16(s0 + 64 * LD, lds + lb + 4096);
  };

  f32x4 acc[8][4];
  #pragma unroll
  for (int i = 0; i < 8; ++i)
    #pragma unroll
    for (int j = 0; j < 4; ++j)
      acc[i][j] = (f32x4)(0.0f);

  s16x8 afr[2][2], bfr[4][2];

#define LOADB(d)                                                              \
  _Pragma("unroll") for (int ni = 0; ni < 4; ++ni)                            \
    _Pragma("unroll") for (int kk = 0; kk < 2; ++kk) {                        \
      const int nr = wn * 64 + ni * 16 + fr;                                  \
      int u = (d) * 32768 + 16384 + (nr >> 7) * 8192 + (nr & 127) * 64        \
              + kk * 32 + ko;                                                 \
      u ^= ((u >> 8) & 1) << 5;                                               \
      bfr[ni][kk] = *(const s16x8*)&lds[u];                                   \
    }

#define PHASE(d, q, DOB, STAGE, VM)                                           \
  {                                                                           \
    if (DOB) { LOADB(d) }                                                     \
    _Pragma("unroll") for (int ai = 0; ai < 2; ++ai)                          \
      _Pragma("unroll") for (int kk = 0; kk < 2; ++kk) {                      \
        int u = (d) * 32768 + wm * 8192 + ((2 * (q) + ai) * 16 + fr) * 64     \
                + kk * 32 + ko;                                               \
        u ^= ((u >> 8) & 1) << 5;                                             \
        afr[ai][kk] = *(const s16x8*)&lds[u];                                 \
      }                                                                       \
    STAGE;                                                                    \
    __builtin_amdgcn_s_barrier();                                             \
    asm volatile("s_waitcnt lgkmcnt(0)" ::: "memory");                        \
    __builtin_amdgcn_sched_barrier(0);                                        \
    __builtin_amdgcn_s_setprio(1);                                            \
    _Pragma("unroll") for (int ai = 0; ai < 2; ++ai)                          \
      _Pragma("unroll") for (int ni = 0; ni < 4; ++ni)                        \
        _Pragma("unroll") for (int kk = 0; kk < 2; ++kk)                      \
          acc[2 * (q) + ai][ni] =                                             \
              mfma16<DT>(afr[ai][kk], bfr[ni][kk], acc[2 * (q) + ai][ni]);    \
    __builtin_amdgcn_s_setprio(0);                                            \
    if (VM) { asm volatile("s_waitcnt vmcnt(6)" ::: "memory"); }              \
    __builtin_amdgcn_s_barrier();                                             \
  }

  // prologue: stage tile0 fully + tile1 {B0,B1,A0}; wait; barrier
  sB(0, 0, 0); sB(0, 1, 0);
  sA(0, 0, 0); sA(0, 1, 0);
  sB(1, 0, 64); sB(1, 1, 64);
  sA(1, 0, 64);
  asm volatile("s_waitcnt vmcnt(6)" ::: "memory");
  __builtin_amdgcn_s_barrier();

  for (int i = 0; i < NI; ++i) {
    const int a1c = (2 * i + 1) << 6;
    const int c0  = ((2 * i + 2 < NT) ? 2 * i + 2 : NT - 1) << 6;
    const int c1  = ((2 * i + 3 < NT) ? 2 * i + 3 : NT - 1) << 6;
    PHASE(0, 0, true,  sA(1, 1, a1c), false)
    PHASE(0, 1, false, sB(0, 0, c0), false)
    PHASE(0, 2, false, sB(0, 1, c0), false)
    PHASE(0, 3, false, sA(0, 0, c0), true)
    PHASE(1, 0, true,  sA(0, 1, c0), false)
    PHASE(1, 1, false, sB(1, 0, c1), false)
    PHASE(1, 2, false, sB(1, 1, c1), false)
    PHASE(1, 3, false, sA(1, 0, c1), true)
  }
#undef PHASE
#undef LOADB

  // epilogue: C/D frag col = lane&15 (N side), row = (lane>>4)*4 + r (M side)
  const int rg = (lane >> 4) * 4;
  #pragma unroll
  for (int ni = 0; ni < 4; ++ni) {
    const int gn = n0 + wn * 64 + ni * 16 + fr;
    const float bvl = bias[gn];
    #pragma unroll
    for (int mi = 0; mi < 8; ++mi) {
      const int gmB = m0 + wm * 128 + mi * 16 + rg;
      f32x4 v = acc[mi][ni];
      if (OM == 0) {
        float* Cf = (float*)Cp;
        #pragma unroll
        for (int r = 0; r < 4; ++r)
          Cf[(long)(gmB + r) * LDC + gn] = v[r] + bvl;
      } else { // OM == 1: vT[((b*8+h)*256 + i)*256 + s]
        const int b = gmB >> 8, s = gmB & 255, h = gn >> 8, ii = gn & 255;
        u16x4 o;
        #pragma unroll
        for (int r = 0; r < 4; ++r) o[r] = f2bf(v[r] + bvl);
        *(u16x4*)&((unsigned short*)Cp)[((long)((b * 8 + h) * 256 + ii) << 8) + s] = o;
      }
    }
  }
}

// ---------------- 128x128 NT GEMM (m97 structure) — aggregation ----------------
template<int MODE, int OM, bool BATCHED>
__global__ __launch_bounds__(256)
void fgemm(const unsigned short* __restrict__ A, const unsigned short* __restrict__ B,
           const float* __restrict__ bias, void* __restrict__ C,
           int lda, int ldb, int ldc, int KT)
{
  __shared__ __align__(16) unsigned short lA[2 * 128 * 32];
  __shared__ __align__(16) unsigned short lB[2 * 128 * 32];

  const int tid  = threadIdx.x;
  const int lane = tid & 63;
  const int wid  = tid >> 6;
  const int wr   = wid >> 1;
  const int wc   = wid & 1;

  const int z  = BATCHED ? blockIdx.z : 0;
  const int m0 = blockIdx.y * 128;
  const int n0 = blockIdx.x * 128;

  long aBase = (long)m0 * lda;
  long bBase = (long)n0 * ldb;
  if (BATCHED) {
    aBase += (long)z * 256 * lda;
    bBase += (long)z * 256 * ldb;
  }

  const int ar0 = tid >> 2, ac0 = (tid & 3) * 8;
  const int ar1 = ar0 + 64, ac1 = ac0;

  const unsigned short* pa0 = A + aBase + (long)ar0 * lda + ac0;
  const unsigned short* pa1 = A + aBase + (long)ar1 * lda + ac1;
  const unsigned short* pb0 = B + bBase + (long)ar0 * ldb + ac0;
  const unsigned short* pb1 = B + bBase + (long)ar1 * ldb + ac1;

  constexpr int SUBOFF = (MODE == 0) ? 2048 : 32;
  constexpr int KSTEP  = (MODE == 0) ? 32 : 64;

  f32x4 acc[4][4];
  #pragma unroll
  for (int i = 0; i < 4; ++i)
    #pragma unroll
    for (int j = 0; j < 4; ++j)
      acc[i][j] = (f32x4)(0.0f);

  const int fr   = lane & 15;
  const int krow = (lane >> 4) * 8;

  for (int kt = 0; kt < KT; kt += KSTEP) {
    gload16(pa0 + kt,          lA + tid * 8);
    gload16(pa1 + kt,          lA + (tid + 256) * 8);
    gload16(pa0 + kt + SUBOFF, lA + 4096 + tid * 8);
    gload16(pa1 + kt + SUBOFF, lA + 4096 + (tid + 256) * 8);
    gload16(pb0 + kt,          lB + tid * 8);
    gload16(pb1 + kt,          lB + (tid + 256) * 8);
    gload16(pb0 + kt + SUBOFF, lB + 4096 + tid * 8);
    gload16(pb1 + kt + SUBOFF, lB + 4096 + (tid + 256) * 8);
    __syncthreads();

    s16x8 a0[4], a1[4], b0[4], b1[4];
    #pragma unroll
    for (int i = 0; i < 4; ++i) {
      const int r = (wr * 64 + i * 16 + fr) * 32 + krow;
      a0[i] = *(const s16x8*)&lA[r];
      a1[i] = *(const s16x8*)&lA[4096 + r];
    }
    #pragma unroll
    for (int j = 0; j < 4; ++j) {
      const int r = (wc * 64 + j * 16 + fr) * 32 + krow;
      b0[j] = *(const s16x8*)&lB[r];
      b1[j] = *(const s16x8*)&lB[4096 + r];
    }

    #pragma unroll
    for (int i = 0; i < 4; ++i)
      #pragma unroll
      for (int j = 0; j < 4; ++j) {
        if (MODE == 0) {
          acc[i][j] = __builtin_amdgcn_mfma_f32_16x16x32_bf16(a1[i], b0[j], acc[i][j], 0, 0, 0);
          acc[i][j] = __builtin_amdgcn_mfma_f32_16x16x32_bf16(a0[i], b1[j], acc[i][j], 0, 0, 0);
          acc[i][j] = __builtin_amdgcn_mfma_f32_16x16x32_bf16(a0[i], b0[j], acc[i][j], 0, 0, 0);
        } else {
          acc[i][j] = __builtin_amdgcn_mfma_f32_16x16x32_bf16(a0[i], b0[j], acc[i][j], 0, 0, 0);
          acc[i][j] = __builtin_amdgcn_mfma_f32_16x16x32_bf16(a1[i], b1[j], acc[i][j], 0, 0, 0);
        }
      }

    __syncthreads();
  }

  const int rg = (lane >> 4) * 4;
  #pragma unroll
  for (int j = 0; j < 4; ++j) {
    const int gn = n0 + wc * 64 + j * 16 + fr;
    const float bvl = bias ? bias[gn] : 0.0f;
    #pragma unroll
    for (int i = 0; i < 4; ++i) {
      const int gmB = m0 + wr * 64 + i * 16 + rg;
      f32x4 v = acc[i][j];
      if (OM == 0) {
        float* Cf = (float*)C;
        #pragma unroll
        for (int r = 0; r < 4; ++r)
          Cf[(long)(gmB + r) * ldc + gn] = v[r] + bvl;
      } else if (OM == 2) {
        long cb = 0;
        if (BATCHED) cb = (long)(z >> 3) * 256 * ldc + (long)(z & 7) * 256;
        unsigned short* Ch = (unsigned short*)C;
        #pragma unroll
        for (int r = 0; r < 4; ++r)
          Ch[cb + (long)(gmB + r) * ldc + gn] = f2bf(v[r] + bvl);
      } else {
        const int b = gmB >> 8, s = gmB & 255, h = gn >> 8, ii = gn & 255;
        u16x4 o;
        #pragma unroll
        for (int r = 0; r < 4; ++r) o[r] = f2bf(v[r] + bvl);
        *(u16x4*)&((unsigned short*)C)[((long)((b * 8 + h) * 256 + ii) << 8) + s] = o;
      }
    }
  }
}

// ---------------- circular correlation + softmax ----------------
// one wave per (b,h,l) row; rolling Q-window: per 4-u step = 1 uniform K read
// (bank-broadcast) + 1 per-lane Q read (stride-16B, conflict-free) + 16 FMA.
__global__ __launch_bounds__(256)
void corr_softmax(const float* __restrict__ qp, const float* __restrict__ kp0,
                  const float* __restrict__ kp1, const float* __restrict__ temp,
                  unsigned short* __restrict__ w)
{
  __shared__ float qs[4][520];   // q duplicated [0..511]
  __shared__ float ks[4][264];
  const int tid  = threadIdx.x;
  const int lane = tid & 63;
  const int wid  = tid >> 6;
  const int row  = blockIdx.x * 4 + wid;       // ((b*8+h)*256+l)
  const int b = row >> 11;
  const int h = (row >> 8) & 7;
  const int l = row & 255;
  const long qbase = ((long)(b * 256 + l) << 11) + h * 256;
  const float* kb  = (b < 16) ? kp0 : kp1;
  const long kbase = ((long)((b & 15) * 256 + l) << 11) + h * 256;

  {
    f32x4 qv = *(const f32x4*)(qp + qbase + 4 * lane);
    f32x4 kv = *(const f32x4*)(kb + kbase + 4 * lane);
    *(f32x4*)&qs[wid][4 * lane]       = qv;
    *(f32x4*)&qs[wid][256 + 4 * lane] = qv;
    *(f32x4*)&ks[wid][4 * lane]       = kv;
  }
  __syncthreads();

  float c0 = 0.f, c1 = 0.f, c2 = 0.f, c3 = 0.f;
  const int d = 4 * lane;
  const float* Q  = &qs[wid][0];
  const float* Kv = &ks[wid][0];
  f32x4 qa = *(const f32x4*)(Q + d);             // rolling window Q[u0+d .. +3]
  #pragma unroll 4
  for (int u0 = 0; u0 < 256; u0 += 4) {
    f32x4 k4 = *(const f32x4*)(Kv + u0);         // uniform -> broadcast
    f32x4 qb = *(const f32x4*)(Q + u0 + d + 4);  // max idx 511, in-bounds
    c0 += k4[0]*qa[0] + k4[1]*qa[1] + k4[2]*qa[2] + k4[3]*qa[3];
    c1 += k4[0]*qa[1] + k4[1]*qa[2] + k4[2]*qa[3] + k4[3]*qb[0];
    c2 += k4[0]*qa[2] + k4[1]*qa[3] + k4[2]*qb[0] + k4[3]*qb[1];
    c3 += k4[0]*qa[3] + k4[1]*qb[0] + k4[2]*qb[1] + k4[3]*qb[2];
    qa = qb;
  }

  const float invT = 1.0f / temp[h];
  float mx = fmaxf(fmaxf(c0, c1), fmaxf(c2, c3));
  #pragma unroll
  for (int off = 32; off >= 1; off >>= 1) mx = fmaxf(mx, __shfl_xor(mx, off, 64));
  const float e0 = __expf((c0 - mx) * invT);
  const float e1 = __expf((c1 - mx) * invT);
  const float e2 = __expf((c2 - mx) * invT);
  const float e3 = __expf((c3 - mx) * invT);
  float sm = e0 + e1 + e2 + e3;
  #pragma unroll
  for (int off = 32; off >= 1; off >>= 1) sm += __shfl_xor(sm, off, 64);
  const float rs = 1.0f / sm;
  u16x4 o;
  o[0] = f2bf(e0 * rs); o[1] = f2bf(e1 * rs); o[2] = f2bf(e2 * rs); o[3] = f2bf(e3 * rs);
  *(u16x4*)(w + (long)row * 256 + d) = o;
}

// ---------------- launcher ----------------

extern "C" void kernel_launch(void* const* d_in, const int* in_sizes, int n_in,
                              void* d_out, int out_size, void* d_ws, size_t ws_size,
                              hipStream_t stream) {
  (void)in_sizes; (void)n_in; (void)out_size; (void)ws_size;
  const float* queries = (const float*)d_in[0];
  const float* keys    = (const float*)d_in[1];
  const float* values  = (const float*)d_in[2];
  const float* Wq = (const float*)d_in[3];
  const float* bq = (const float*)d_in[4];
  const float* Wk = (const float*)d_in[5];
  const float* bk = (const float*)d_in[6];
  const float* Wv = (const float*)d_in[7];
  const float* bv = (const float*)d_in[8];
  const float* Wo = (const float*)d_in[9];
  const float* bo = (const float*)d_in[10];
  const float* temp = (const float*)d_in[11];

  // workspace (peak 192 MiB) + d_out as W-pack scratch:
  //  ws[0,32)    extA f16 (queries, then keys) -> wgt bf16 after K-GEMM
  //  ws[32,96)   qproj fp32 -> vT[32,64) + out2[64,96) after corr
  //  ws[96,160)  kproj fp32 -> Wob[96,104) after corr
  //  ws[160,192) Vb bf16 (values)
  //  d_out       extW (packed W, <=8 MiB) until the final GEMM
  char* ws = (char*)d_ws;
  auto MB = [](size_t m) { return m << 20; };
  unsigned short* extA = (unsigned short*)ws;
  unsigned short* wgt  = (unsigned short*)ws;
  float*          qproj= (float*)(ws + MB(32));
  unsigned short* vT   = (unsigned short*)(ws + MB(32));
  unsigned short* out2 = (unsigned short*)(ws + MB(64));
  float*          kproj= (float*)(ws + MB(96));
  unsigned short* Wob  = (unsigned short*)(ws + MB(96));
  unsigned short* Vb   = (unsigned short*)(ws + MB(160));
  unsigned short* extW = (unsigned short*)d_out;

  dim3 blk(256);
  dim3 gBig(32, 8);   // 256 blocks; bx -> M (XCD-remapped in-kernel), by -> N

  // ---- Q projection (fp16 single-pass) ----
  pack_f16<<<2048, blk, 0, stream>>>(queries, extA, (long)8192 * 2048 / 8);
  pack_f16<<<2048, blk, 0, stream>>>(Wq, extW, (long)2048 * 2048 / 8);
  gemm8p<1, 0><<<gBig, 512, 0, stream>>>(extA, extW, bq, qproj);
  // ---- K projection (fp16 single-pass) ----
  pack_f16<<<2048, blk, 0, stream>>>(keys, extA, (long)8192 * 2048 / 8);
  pack_f16<<<2048, blk, 0, stream>>>(Wk, extW, (long)2048 * 2048 / 8);
  gemm8p<1, 0><<<gBig, 512, 0, stream>>>(extA, extW, bk, kproj);
  // ---- correlation + softmax -> bf16 weights ----
  corr_softmax<<<dim3(16384), blk, 0, stream>>>(qproj, kproj,
                                                kproj + (long)16 * 256 * 2048, temp, wgt);
  // ---- V projection (bf16), epilogue scatters transposed vT[b,h,i,s] ----
  pack_bf16<<<2048, blk, 0, stream>>>(values, Vb, (long)8192 * 2048 / 8);
  pack_bf16<<<2048, blk, 0, stream>>>(Wv, extW, (long)2048 * 2048 / 8);
  gemm8p<0, 1><<<gBig, 512, 0, stream>>>(Vb, extW, bv, vT);
  // ---- aggregation: out2[b*256+l][h*256+i] = sum_s wgt[bhl][s]*vT[bhi][s] ----
  fgemm<1, 2, true><<<dim3(2, 2, 256), blk, 0, stream>>>(wgt, vT, nullptr, out2,
                                                         256, 256, 2048, 256);
  // ---- O projection -> d_out (fp32) ----
  pack_bf16<<<2048, blk, 0, stream>>>(Wo, Wob, (long)2048 * 2048 / 8);
  gemm8p<0, 0><<<gBig, 512, 0, stream>>>(out2, Wob, bo, (float*)d_out);
}

// Round 10
// 462.013 us; speedup vs baseline: 1.1392x; 1.1392x over previous
//
#include <hip/hip_runtime.h>
#include <stdint.h>

typedef float  f32x4 __attribute__((ext_vector_type(4)));
typedef short  s16x8 __attribute__((ext_vector_type(8)));
typedef _Float16 h16x8 __attribute__((ext_vector_type(8)));
typedef _Float16 h16x2 __attribute__((ext_vector_type(2)));
typedef unsigned short u16x4 __attribute__((ext_vector_type(4)));
typedef unsigned int u32x2 __attribute__((ext_vector_type(2)));
typedef unsigned int u32x4 __attribute__((ext_vector_type(4)));

#define DEV __device__ __forceinline__

DEV unsigned short f2bf(float f) {
  union { float f; unsigned int u; } v; v.f = f;
  unsigned int u = v.u;
  return (unsigned short)((u + 0x7fffu + ((u >> 16) & 1u)) >> 16);
}

typedef const __attribute__((address_space(1))) void* as1cvp;
typedef __attribute__((address_space(3))) void* as3vp;
DEV void gload16(const void* g, void* l) {
  __builtin_amdgcn_global_load_lds((as1cvp)g, (as3vp)l, 16, 0, 0);
}

DEV float fdot2u(unsigned int a, unsigned int b, float c) {
  return __builtin_amdgcn_fdot2(__builtin_bit_cast(h16x2, a),
                                __builtin_bit_cast(h16x2, b), c, false);
}

// ---------------- pack kernels (memory-bound) ----------------

__global__ __launch_bounds__(256) void pack_f16(const float* __restrict__ in,
                                                unsigned short* __restrict__ out, long total8)
{
  for (long t = (long)blockIdx.x * 256 + threadIdx.x; t < total8;
       t += (long)gridDim.x * 256) {
    const float* src = in + t * 8;
    f32x4 x0 = *(const f32x4*)src;
    f32x4 x1 = *(const f32x4*)(src + 4);
    s16x8 h8;
    #pragma unroll
    for (int e = 0; e < 4; ++e) {
      h8[e]     = (short)__builtin_bit_cast(unsigned short, (_Float16)x0[e]);
      h8[e + 4] = (short)__builtin_bit_cast(unsigned short, (_Float16)x1[e]);
    }
    *(s16x8*)(out + t * 8) = h8;
  }
}

__global__ __launch_bounds__(256) void pack_bf16(const float* __restrict__ in,
                                                 unsigned short* __restrict__ out, long total8)
{
  for (long t = (long)blockIdx.x * 256 + threadIdx.x; t < total8;
       t += (long)gridDim.x * 256) {
    const float* src = in + t * 8;
    f32x4 x0 = *(const f32x4*)src;
    f32x4 x1 = *(const f32x4*)(src + 4);
    s16x8 h8;
    #pragma unroll
    for (int e = 0; e < 4; ++e) {
      h8[e]     = (short)f2bf(x0[e]);
      h8[e + 4] = (short)f2bf(x1[e]);
    }
    *(s16x8*)(out + t * 8) = h8;
  }
}

// ---------------- 256x256 8-phase NT GEMM (bf16 or fp16) ----------------
// Grid (32, 8): bx -> M-block via XCD remap; by -> N-block. K = 2048.
// DT 0: bf16 MFMA; DT 1: fp16 MFMA.
// OM 0: fp32 row-major; OM 1: bf16 scatter vT[((b*8+h)*256+i)*256+s];
// OM 2: fp16 row-major.
template<int DT>
DEV f32x4 mfma16(s16x8 a, s16x8 b, f32x4 c) {
  if constexpr (DT == 0)
    return __builtin_amdgcn_mfma_f32_16x16x32_bf16(a, b, c, 0, 0, 0);
  else
    return __builtin_amdgcn_mfma_f32_16x16x32_f16(
        __builtin_bit_cast(h16x8, a), __builtin_bit_cast(h16x8, b), c, 0, 0, 0);
}

template<int DT, int OM>
__global__ __launch_bounds__(512, 2)
void gemm8p(const unsigned short* __restrict__ Ap, const unsigned short* __restrict__ Bp,
            const float* __restrict__ bias, void* __restrict__ Cp)
{
  constexpr int LD  = 2048;
  constexpr int LDC = 2048;
  constexpr int NT  = 32;
  constexpr int NI  = NT / 2;

  __shared__ __align__(16) unsigned short lds[65536];

  const int tid  = threadIdx.x;
  const int lane = tid & 63;
  const int wid  = tid >> 6;
  const int wm   = wid >> 2;
  const int wn   = wid & 3;
  const int fr   = lane & 15;
  const int ko   = (lane >> 4) * 8;

  const int bx = blockIdx.x;
  const int m0 = (((bx & 7) << 2) + (bx >> 3)) * 256;
  const int n0 = blockIdx.y * 256;

  const int sr  = tid >> 3;
  const int scc = (((tid & 7) ^ (((tid >> 5) & 1) << 2)) << 3);

  auto sA = [&](int d, int u, int col) {
    const unsigned short* s0 = Ap + (long)(m0 + u * 64 + sr) * LD + col + scc;
    const int lb = d * 32768 + u * 4096 + (wid << 9);
    gload16(s0, lds + lb);
    gload16(s0 + 128 * LD, lds + lb + 8192);
  };
  auto sB = [&](int d, int h, int col) {
    const unsigned short* s0 = Bp + (long)(n0 + h * 128 + sr) * LD + col + scc;
    const int lb = d * 32768 + 16384 + h * 8192 + (wid << 9);
    gload16(s0, lds + lb);
    gload16(s0 + 64 * LD, lds + lb + 4096);
  };

  f32x4 acc[8][4];
  #pragma unroll
  for (int i = 0; i < 8; ++i)
    #pragma unroll
    for (int j = 0; j < 4; ++j)
      acc[i][j] = (f32x4)(0.0f);

  s16x8 afr[2][2], bfr[4][2];

#define LOADB(d)                                                              \
  _Pragma("unroll") for (int ni = 0; ni < 4; ++ni)                            \
    _Pragma("unroll") for (int kk = 0; kk < 2; ++kk) {                        \
      const int nr = wn * 64 + ni * 16 + fr;                                  \
      int u = (d) * 32768 + 16384 + (nr >> 7) * 8192 + (nr & 127) * 64        \
              + kk * 32 + ko;                                                 \
      u ^= ((u >> 8) & 1) << 5;                                               \
      bfr[ni][kk] = *(const s16x8*)&lds[u];                                   \
    }

#define PHASE(d, q, DOB, STAGE, VM)                                           \
  {                                                                           \
    if (DOB) { LOADB(d) }                                                     \
    _Pragma("unroll") for (int ai = 0; ai < 2; ++ai)                          \
      _Pragma("unroll") for (int kk = 0; kk < 2; ++kk) {                      \
        int u = (d) * 32768 + wm * 8192 + ((2 * (q) + ai) * 16 + fr) * 64     \
                + kk * 32 + ko;                                               \
        u ^= ((u >> 8) & 1) << 5;                                             \
        afr[ai][kk] = *(const s16x8*)&lds[u];                                 \
      }                                                                       \
    STAGE;                                                                    \
    __builtin_amdgcn_s_barrier();                                             \
    asm volatile("s_waitcnt lgkmcnt(0)" ::: "memory");                        \
    __builtin_amdgcn_sched_barrier(0);                                        \
    __builtin_amdgcn_s_setprio(1);                                            \
    _Pragma("unroll") for (int ai = 0; ai < 2; ++ai)                          \
      _Pragma("unroll") for (int ni = 0; ni < 4; ++ni)                        \
        _Pragma("unroll") for (int kk = 0; kk < 2; ++kk)                      \
          acc[2 * (q) + ai][ni] =                                             \
              mfma16<DT>(afr[ai][kk], bfr[ni][kk], acc[2 * (q) + ai][ni]);    \
    __builtin_amdgcn_s_setprio(0);                                            \
    if (VM) { asm volatile("s_waitcnt vmcnt(6)" ::: "memory"); }              \
    __builtin_amdgcn_s_barrier();                                             \
  }

  sB(0, 0, 0); sB(0, 1, 0);
  sA(0, 0, 0); sA(0, 1, 0);
  sB(1, 0, 64); sB(1, 1, 64);
  sA(1, 0, 64);
  asm volatile("s_waitcnt vmcnt(6)" ::: "memory");
  __builtin_amdgcn_s_barrier();

  for (int i = 0; i < NI; ++i) {
    const int a1c = (2 * i + 1) << 6;
    const int c0  = ((2 * i + 2 < NT) ? 2 * i + 2 : NT - 1) << 6;
    const int c1  = ((2 * i + 3 < NT) ? 2 * i + 3 : NT - 1) << 6;
    PHASE(0, 0, true,  sA(1, 1, a1c), false)
    PHASE(0, 1, false, sB(0, 0, c0), false)
    PHASE(0, 2, false, sB(0, 1, c0), false)
    PHASE(0, 3, false, sA(0, 0, c0), true)
    PHASE(1, 0, true,  sA(0, 1, c0), false)
    PHASE(1, 1, false, sB(1, 0, c1), false)
    PHASE(1, 2, false, sB(1, 1, c1), false)
    PHASE(1, 3, false, sA(1, 0, c1), true)
  }
#undef PHASE
#undef LOADB

  const int rg = (lane >> 4) * 4;
  #pragma unroll
  for (int ni = 0; ni < 4; ++ni) {
    const int gn = n0 + wn * 64 + ni * 16 + fr;
    const float bvl = bias[gn];
    #pragma unroll
    for (int mi = 0; mi < 8; ++mi) {
      const int gmB = m0 + wm * 128 + mi * 16 + rg;
      f32x4 v = acc[mi][ni];
      if (OM == 0) {
        float* Cf = (float*)Cp;
        #pragma unroll
        for (int r = 0; r < 4; ++r)
          Cf[(long)(gmB + r) * LDC + gn] = v[r] + bvl;
      } else if (OM == 2) {   // fp16 row-major
        unsigned short* Ch = (unsigned short*)Cp;
        #pragma unroll
        for (int r = 0; r < 4; ++r)
          Ch[(long)(gmB + r) * LDC + gn] =
              __builtin_bit_cast(unsigned short, (_Float16)(v[r] + bvl));
      } else {                // OM == 1: vT scatter (bf16)
        const int b = gmB >> 8, s = gmB & 255, h = gn >> 8, ii = gn & 255;
        u16x4 o;
        #pragma unroll
        for (int r = 0; r < 4; ++r) o[r] = f2bf(v[r] + bvl);
        *(u16x4*)&((unsigned short*)Cp)[((long)((b * 8 + h) * 256 + ii) << 8) + s] = o;
      }
    }
  }
}

// ---------------- 128x128 NT GEMM (m97 structure) — aggregation ----------------
template<int MODE, int OM, bool BATCHED>
__global__ __launch_bounds__(256)
void fgemm(const unsigned short* __restrict__ A, const unsigned short* __restrict__ B,
           const float* __restrict__ bias, void* __restrict__ C,
           int lda, int ldb, int ldc, int KT)
{
  __shared__ __align__(16) unsigned short lA[2 * 128 * 32];
  __shared__ __align__(16) unsigned short lB[2 * 128 * 32];

  const int tid  = threadIdx.x;
  const int lane = tid & 63;
  const int wid  = tid >> 6;
  const int wr   = wid >> 1;
  const int wc   = wid & 1;

  const int z  = BATCHED ? blockIdx.z : 0;
  const int m0 = blockIdx.y * 128;
  const int n0 = blockIdx.x * 128;

  long aBase = (long)m0 * lda;
  long bBase = (long)n0 * ldb;
  if (BATCHED) {
    aBase += (long)z * 256 * lda;
    bBase += (long)z * 256 * ldb;
  }

  const int ar0 = tid >> 2, ac0 = (tid & 3) * 8;
  const int ar1 = ar0 + 64, ac1 = ac0;

  const unsigned short* pa0 = A + aBase + (long)ar0 * lda + ac0;
  const unsigned short* pa1 = A + aBase + (long)ar1 * lda + ac1;
  const unsigned short* pb0 = B + bBase + (long)ar0 * ldb + ac0;
  const unsigned short* pb1 = B + bBase + (long)ar1 * ldb + ac1;

  constexpr int SUBOFF = (MODE == 0) ? 2048 : 32;
  constexpr int KSTEP  = (MODE == 0) ? 32 : 64;

  f32x4 acc[4][4];
  #pragma unroll
  for (int i = 0; i < 4; ++i)
    #pragma unroll
    for (int j = 0; j < 4; ++j)
      acc[i][j] = (f32x4)(0.0f);

  const int fr   = lane & 15;
  const int krow = (lane >> 4) * 8;

  for (int kt = 0; kt < KT; kt += KSTEP) {
    gload16(pa0 + kt,          lA + tid * 8);
    gload16(pa1 + kt,          lA + (tid + 256) * 8);
    gload16(pa0 + kt + SUBOFF, lA + 4096 + tid * 8);
    gload16(pa1 + kt + SUBOFF, lA + 4096 + (tid + 256) * 8);
    gload16(pb0 + kt,          lB + tid * 8);
    gload16(pb1 + kt,          lB + (tid + 256) * 8);
    gload16(pb0 + kt + SUBOFF, lB + 4096 + tid * 8);
    gload16(pb1 + kt + SUBOFF, lB + 4096 + (tid + 256) * 8);
    __syncthreads();

    s16x8 a0[4], a1[4], b0[4], b1[4];
    #pragma unroll
    for (int i = 0; i < 4; ++i) {
      const int r = (wr * 64 + i * 16 + fr) * 32 + krow;
      a0[i] = *(const s16x8*)&lA[r];
      a1[i] = *(const s16x8*)&lA[4096 + r];
    }
    #pragma unroll
    for (int j = 0; j < 4; ++j) {
      const int r = (wc * 64 + j * 16 + fr) * 32 + krow;
      b0[j] = *(const s16x8*)&lB[r];
      b1[j] = *(const s16x8*)&lB[4096 + r];
    }

    #pragma unroll
    for (int i = 0; i < 4; ++i)
      #pragma unroll
      for (int j = 0; j < 4; ++j) {
        if (MODE == 0) {
          acc[i][j] = __builtin_amdgcn_mfma_f32_16x16x32_bf16(a1[i], b0[j], acc[i][j], 0, 0, 0);
          acc[i][j] = __builtin_amdgcn_mfma_f32_16x16x32_bf16(a0[i], b1[j], acc[i][j], 0, 0, 0);
          acc[i][j] = __builtin_amdgcn_mfma_f32_16x16x32_bf16(a0[i], b0[j], acc[i][j], 0, 0, 0);
        } else {
          acc[i][j] = __builtin_amdgcn_mfma_f32_16x16x32_bf16(a0[i], b0[j], acc[i][j], 0, 0, 0);
          acc[i][j] = __builtin_amdgcn_mfma_f32_16x16x32_bf16(a1[i], b1[j], acc[i][j], 0, 0, 0);
        }
      }

    __syncthreads();
  }

  const int rg = (lane >> 4) * 4;
  #pragma unroll
  for (int j = 0; j < 4; ++j) {
    const int gn = n0 + wc * 64 + j * 16 + fr;
    const float bvl = bias ? bias[gn] : 0.0f;
    #pragma unroll
    for (int i = 0; i < 4; ++i) {
      const int gmB = m0 + wr * 64 + i * 16 + rg;
      f32x4 v = acc[i][j];
      if (OM == 0) {
        float* Cf = (float*)C;
        #pragma unroll
        for (int r = 0; r < 4; ++r)
          Cf[(long)(gmB + r) * ldc + gn] = v[r] + bvl;
      } else if (OM == 2) {
        long cb = 0;
        if (BATCHED) cb = (long)(z >> 3) * 256 * ldc + (long)(z & 7) * 256;
        unsigned short* Ch = (unsigned short*)C;
        #pragma unroll
        for (int r = 0; r < 4; ++r)
          Ch[cb + (long)(gmB + r) * ldc + gn] = f2bf(v[r] + bvl);
      } else {
        const int b = gmB >> 8, s = gmB & 255, h = gn >> 8, ii = gn & 255;
        u16x4 o;
        #pragma unroll
        for (int r = 0; r < 4; ++r) o[r] = f2bf(v[r] + bvl);
        *(u16x4*)&((unsigned short*)C)[((long)((b * 8 + h) * 256 + ii) << 8) + s] = o;
      }
    }
  }
}

// ---------------- circular correlation + softmax (fp16 dot2, shifted-Q) ----------------
// one wave per (b,h,l) row; lane owns lags d=4*lane..d+3, e = 2*lane.
//  even D: c_D = sum_v fdot2(K2[v], Q2[v + D/2])         v=0..127
//  odd  D: c_D = sum_v fdot2(K2[v], Q2s[v + (D-1)/2])    Q2s from qs2[i]=q[i+1]
// No boundary terms, no K padding, no in-register shifts. qs/qs2 duplicated
// [0..511] for circular wrap; qs2 built at staging with one __shfl (lane+1).
__global__ __launch_bounds__(256)
void corr_softmax(const unsigned short* __restrict__ qp,
                  const unsigned short* __restrict__ kp,
                  const float* __restrict__ temp, unsigned short* __restrict__ w)
{
  __shared__ __align__(16) unsigned short qs[4][520];  // q
  __shared__ __align__(16) unsigned short q2[4][520];  // q shifted by 1
  __shared__ __align__(16) unsigned short ks[4][264];  // k
  const int tid  = threadIdx.x;
  const int lane = tid & 63;
  const int wid  = tid >> 6;
  const int row  = blockIdx.x * 4 + wid;       // ((b*8+h)*256+l)
  const int b = row >> 11;
  const int h = (row >> 8) & 7;
  const int l = row & 255;
  const long base = ((long)(b * 256 + l) << 11) + h * 256;

  {
    u16x4 qv = *(const u16x4*)(qp + base + 4 * lane);
    u16x4 kv = *(const u16x4*)(kp + base + 4 * lane);
    const int nxt = __shfl((int)(unsigned int)(unsigned short)qv[0],
                           (lane + 1) & 63, 64);
    u16x4 qsv;
    qsv[0] = qv[1]; qsv[1] = qv[2]; qsv[2] = qv[3];
    qsv[3] = (unsigned short)(unsigned int)nxt;   // q[4*lane+4] (wraps to q[0])
    *(u16x4*)&qs[wid][4 * lane]       = qv;
    *(u16x4*)&qs[wid][256 + 4 * lane] = qv;
    *(u16x4*)&q2[wid][4 * lane]       = qsv;
    *(u16x4*)&q2[wid][256 + 4 * lane] = qsv;
    *(u16x4*)&ks[wid][4 * lane]       = kv;
  }
  __syncthreads();

  const unsigned short* Q  = &qs[wid][0];
  const unsigned short* Qs = &q2[wid][0];
  const unsigned short* K  = &ks[wid][0];
  const int e = 2 * lane;

  u32x2 A  = *(const u32x2*)&Q[2 * e];          // Q2[e], Q2[e+1]
  u32x2 B  = *(const u32x2*)&Q[2 * (e + 2)];
  u32x2 C  = *(const u32x2*)&Q[2 * (e + 4)];
  u32x2 A2 = *(const u32x2*)&Qs[2 * e];         // Q2s[e], Q2s[e+1]
  u32x2 B2 = *(const u32x2*)&Qs[2 * (e + 2)];
  u32x2 C2 = *(const u32x2*)&Qs[2 * (e + 4)];

  float c0 = 0.f, c1 = 0.f, c2 = 0.f, c3 = 0.f;

  #pragma unroll 2
  for (int t = 0; t < 32; ++t) {
    u32x4 Kw = *(const u32x4*)&K[8 * t];        // K2[4t..4t+3], uniform
    const unsigned int p0 = A[0],  p1 = A[1],  p2 = B[0],  p3 = B[1],  p4 = C[0];
    const unsigned int s0 = A2[0], s1 = A2[1], s2 = B2[0], s3 = B2[1], s4 = C2[0];
    c0 = fdot2u(Kw[0], p0, c0); c2 = fdot2u(Kw[0], p1, c2);
    c1 = fdot2u(Kw[0], s0, c1); c3 = fdot2u(Kw[0], s1, c3);
    c0 = fdot2u(Kw[1], p1, c0); c2 = fdot2u(Kw[1], p2, c2);
    c1 = fdot2u(Kw[1], s1, c1); c3 = fdot2u(Kw[1], s2, c3);
    c0 = fdot2u(Kw[2], p2, c0); c2 = fdot2u(Kw[2], p3, c2);
    c1 = fdot2u(Kw[2], s2, c1); c3 = fdot2u(Kw[2], s3, c3);
    c0 = fdot2u(Kw[3], p3, c0); c2 = fdot2u(Kw[3], p4, c2);
    c1 = fdot2u(Kw[3], s3, c1); c3 = fdot2u(Kw[3], s4, c3);
    A = C;  A2 = C2;
    B  = *(const u32x2*)&Q[2 * (4 * t + e + 6)];
    C  = *(const u32x2*)&Q[2 * (4 * t + e + 8)];
    B2 = *(const u32x2*)&Qs[2 * (4 * t + e + 6)];
    C2 = *(const u32x2*)&Qs[2 * (4 * t + e + 8)];
  }

  const float invT = 1.0f / temp[h];
  float mx = fmaxf(fmaxf(c0, c1), fmaxf(c2, c3));
  #pragma unroll
  for (int off = 32; off >= 1; off >>= 1) mx = fmaxf(mx, __shfl_xor(mx, off, 64));
  const float e0 = __expf((c0 - mx) * invT);
  const float e1 = __expf((c1 - mx) * invT);
  const float e2 = __expf((c2 - mx) * invT);
  const float e3 = __expf((c3 - mx) * invT);
  float sm = e0 + e1 + e2 + e3;
  #pragma unroll
  for (int off = 32; off >= 1; off >>= 1) sm += __shfl_xor(sm, off, 64);
  const float rs = 1.0f / sm;
  u16x4 o;
  o[0] = f2bf(e0 * rs); o[1] = f2bf(e1 * rs); o[2] = f2bf(e2 * rs); o[3] = f2bf(e3 * rs);
  *(u16x4*)(w + (long)row * 256 + 4 * lane) = o;
}

// ---------------- launcher ----------------

extern "C" void kernel_launch(void* const* d_in, const int* in_sizes, int n_in,
                              void* d_out, int out_size, void* d_ws, size_t ws_size,
                              hipStream_t stream) {
  (void)in_sizes; (void)n_in; (void)out_size; (void)ws_size;
  const float* queries = (const float*)d_in[0];
  const float* keys    = (const float*)d_in[1];
  const float* values  = (const float*)d_in[2];
  const float* Wq = (const float*)d_in[3];
  const float* bq = (const float*)d_in[4];
  const float* Wk = (const float*)d_in[5];
  const float* bk = (const float*)d_in[6];
  const float* Wv = (const float*)d_in[7];
  const float* bv = (const float*)d_in[8];
  const float* Wo = (const float*)d_in[9];
  const float* bo = (const float*)d_in[10];
  const float* temp = (const float*)d_in[11];

  // workspace (peak 136 MiB) + d_out as W-pack scratch:
  //  ws[0,32)    extA (f16 queries/keys; then bf16 values)
  //  ws[32,64)   qproj f16 -> vT bf16 (after corr)
  //  ws[64,96)   kproj f16 -> out2 bf16 (after corr)
  //  ws[96,128)  wgt bf16
  //  ws[128,136) Wob bf16
  //  d_out       extW (packed W, 8 MiB) until the final GEMM
  char* ws = (char*)d_ws;
  auto MB = [](size_t m) { return m << 20; };
  unsigned short* extA = (unsigned short*)ws;
  unsigned short* Vb   = (unsigned short*)ws;
  unsigned short* qproj= (unsigned short*)(ws + MB(32));
  unsigned short* vT   = (unsigned short*)(ws + MB(32));
  unsigned short* kproj= (unsigned short*)(ws + MB(64));
  unsigned short* out2 = (unsigned short*)(ws + MB(64));
  unsigned short* wgt  = (unsigned short*)(ws + MB(96));
  unsigned short* Wob  = (unsigned short*)(ws + MB(128));
  unsigned short* extW = (unsigned short*)d_out;

  dim3 blk(256);
  dim3 gBig(32, 8);

  // ---- Q projection (fp16 in, fp16 out) ----
  pack_f16<<<2048, blk, 0, stream>>>(queries, extA, (long)8192 * 2048 / 8);
  pack_f16<<<2048, blk, 0, stream>>>(Wq, extW, (long)2048 * 2048 / 8);
  gemm8p<1, 2><<<gBig, 512, 0, stream>>>(extA, extW, bq, qproj);
  // ---- K projection (fp16 in, fp16 out) ----
  pack_f16<<<2048, blk, 0, stream>>>(keys, extA, (long)8192 * 2048 / 8);
  pack_f16<<<2048, blk, 0, stream>>>(Wk, extW, (long)2048 * 2048 / 8);
  gemm8p<1, 2><<<gBig, 512, 0, stream>>>(extA, extW, bk, kproj);
  // ---- correlation + softmax -> bf16 weights ----
  corr_softmax<<<dim3(16384), blk, 0, stream>>>(qproj, kproj, temp, wgt);
  // ---- V projection (bf16), epilogue scatters transposed vT[b,h,i,s] ----
  pack_bf16<<<2048, blk, 0, stream>>>(values, Vb, (long)8192 * 2048 / 8);
  pack_bf16<<<2048, blk, 0, stream>>>(Wv, extW, (long)2048 * 2048 / 8);
  gemm8p<0, 1><<<gBig, 512, 0, stream>>>(Vb, extW, bv, vT);
  // ---- aggregation: out2[b*256+l][h*256+i] = sum_s wgt[bhl][s]*vT[bhi][s] ----
  fgemm<1, 2, true><<<dim3(2, 2, 256), blk, 0, stream>>>(wgt, vT, nullptr, out2,
                                                         256, 256, 2048, 256);
  // ---- O projection -> d_out (fp32) ----
  pack_bf16<<<2048, blk, 0, stream>>>(Wo, Wob, (long)2048 * 2048 / 8);
  gemm8p<0, 0><<<gBig, 512, 0, stream>>>(out2, Wob, bo, (float*)d_out);
}

// Round 11
// 455.977 us; speedup vs baseline: 1.1543x; 1.0132x over previous
//
#include <hip/hip_runtime.h>
#include <stdint.h>

typedef float  f32x4 __attribute__((ext_vector_type(4)));
typedef short  s16x8 __attribute__((ext_vector_type(8)));
typedef _Float16 h16x8 __attribute__((ext_vector_type(8)));
typedef _Float16 h16x2 __attribute__((ext_vector_type(2)));
typedef unsigned short u16x4 __attribute__((ext_vector_type(4)));
typedef unsigned int u32x2 __attribute__((ext_vector_type(2)));
typedef unsigned int u32x4 __attribute__((ext_vector_type(4)));

#define DEV __device__ __forceinline__

DEV unsigned short f2bf(float f) {
  union { float f; unsigned int u; } v; v.f = f;
  unsigned int u = v.u;
  return (unsigned short)((u + 0x7fffu + ((u >> 16) & 1u)) >> 16);
}

typedef const __attribute__((address_space(1))) void* as1cvp;
typedef __attribute__((address_space(3))) void* as3vp;
DEV void gload16(const void* g, void* l) {
  __builtin_amdgcn_global_load_lds((as1cvp)g, (as3vp)l, 16, 0, 0);
}

DEV float fdot2u(unsigned int a, unsigned int b, float c) {
  return __builtin_amdgcn_fdot2(__builtin_bit_cast(h16x2, a),
                                __builtin_bit_cast(h16x2, b), c, false);
}

// ---------------- pack kernel: 3 segments, per-segment dtype ----------------
// MODE 0 = bf16, 1 = fp16. Counts are in groups of 8 elements.
template<int M0, int M1, int M2>
__global__ __launch_bounds__(256)
void pack3(const float* __restrict__ in0, unsigned short* __restrict__ out0, long n0,
           const float* __restrict__ in1, unsigned short* __restrict__ out1, long n1,
           const float* __restrict__ in2, unsigned short* __restrict__ out2, long n2)
{
  const long total = n0 + n1 + n2;
  for (long t = (long)blockIdx.x * 256 + threadIdx.x; t < total;
       t += (long)gridDim.x * 256) {
    const float* src; unsigned short* dst; long i; int mode;
    if (t < n0)           { src = in0; dst = out0; i = t;           mode = M0; }
    else if (t < n0 + n1) { src = in1; dst = out1; i = t - n0;      mode = M1; }
    else                  { src = in2; dst = out2; i = t - n0 - n1; mode = M2; }
    f32x4 x0 = *(const f32x4*)(src + i * 8);
    f32x4 x1 = *(const f32x4*)(src + i * 8 + 4);
    s16x8 h8;
    #pragma unroll
    for (int e = 0; e < 4; ++e) {
      if (mode == 1) {
        h8[e]     = (short)__builtin_bit_cast(unsigned short, (_Float16)x0[e]);
        h8[e + 4] = (short)__builtin_bit_cast(unsigned short, (_Float16)x1[e]);
      } else {
        h8[e]     = (short)f2bf(x0[e]);
        h8[e + 4] = (short)f2bf(x1[e]);
      }
    }
    *(s16x8*)(dst + i * 8) = h8;
  }
}

// ---------------- 256x256 8-phase NT GEMM (bf16 or fp16) ----------------
// Grid (32, 8): bx -> M-block via XCD remap; by -> N-block. K = 2048.
// DT 0: bf16 MFMA; DT 1: fp16 MFMA.
// OM 0: fp32 row-major; OM 1: bf16 scatter vT[((b*8+h)*256+i)*256+s];
// OM 2: fp16 row-major.
template<int DT>
DEV f32x4 mfma16(s16x8 a, s16x8 b, f32x4 c) {
  if constexpr (DT == 0)
    return __builtin_amdgcn_mfma_f32_16x16x32_bf16(a, b, c, 0, 0, 0);
  else
    return __builtin_amdgcn_mfma_f32_16x16x32_f16(
        __builtin_bit_cast(h16x8, a), __builtin_bit_cast(h16x8, b), c, 0, 0, 0);
}

template<int DT, int OM>
__global__ __launch_bounds__(512, 2)
void gemm8p(const unsigned short* __restrict__ Ap, const unsigned short* __restrict__ Bp,
            const float* __restrict__ bias, void* __restrict__ Cp)
{
  constexpr int LD  = 2048;
  constexpr int LDC = 2048;
  constexpr int NT  = 32;
  constexpr int NI  = NT / 2;

  __shared__ __align__(16) unsigned short lds[65536];

  const int tid  = threadIdx.x;
  const int lane = tid & 63;
  const int wid  = tid >> 6;
  const int wm   = wid >> 2;
  const int wn   = wid & 3;
  const int fr   = lane & 15;
  const int ko   = (lane >> 4) * 8;

  const int bx = blockIdx.x;
  const int m0 = (((bx & 7) << 2) + (bx >> 3)) * 256;
  const int n0 = blockIdx.y * 256;

  const int sr  = tid >> 3;
  const int scc = (((tid & 7) ^ (((tid >> 5) & 1) << 2)) << 3);

  auto sA = [&](int d, int u, int col) {
    const unsigned short* s0 = Ap + (long)(m0 + u * 64 + sr) * LD + col + scc;
    const int lb = d * 32768 + u * 4096 + (wid << 9);
    gload16(s0, lds + lb);
    gload16(s0 + 128 * LD, lds + lb + 8192);
  };
  auto sB = [&](int d, int h, int col) {
    const unsigned short* s0 = Bp + (long)(n0 + h * 128 + sr) * LD + col + scc;
    const int lb = d * 32768 + 16384 + h * 8192 + (wid << 9);
    gload16(s0, lds + lb);
    gload16(s0 + 64 * LD, lds + lb + 4096);
  };

  f32x4 acc[8][4];
  #pragma unroll
  for (int i = 0; i < 8; ++i)
    #pragma unroll
    for (int j = 0; j < 4; ++j)
      acc[i][j] = (f32x4)(0.0f);

  s16x8 afr[2][2], bfr[4][2];

#define LOADB(d)                                                              \
  _Pragma("unroll") for (int ni = 0; ni < 4; ++ni)                            \
    _Pragma("unroll") for (int kk = 0; kk < 2; ++kk) {                        \
      const int nr = wn * 64 + ni * 16 + fr;                                  \
      int u = (d) * 32768 + 16384 + (nr >> 7) * 8192 + (nr & 127) * 64        \
              + kk * 32 + ko;                                                 \
      u ^= ((u >> 8) & 1) << 5;                                               \
      bfr[ni][kk] = *(const s16x8*)&lds[u];                                   \
    }

#define PHASE(d, q, DOB, STAGE, VM)                                           \
  {                                                                           \
    if (DOB) { LOADB(d) }                                                     \
    _Pragma("unroll") for (int ai = 0; ai < 2; ++ai)                          \
      _Pragma("unroll") for (int kk = 0; kk < 2; ++kk) {                      \
        int u = (d) * 32768 + wm * 8192 + ((2 * (q) + ai) * 16 + fr) * 64     \
                + kk * 32 + ko;                                               \
        u ^= ((u >> 8) & 1) << 5;                                             \
        afr[ai][kk] = *(const s16x8*)&lds[u];                                 \
      }                                                                       \
    STAGE;                                                                    \
    __builtin_amdgcn_s_barrier();                                             \
    asm volatile("s_waitcnt lgkmcnt(0)" ::: "memory");                        \
    __builtin_amdgcn_sched_barrier(0);                                        \
    __builtin_amdgcn_s_setprio(1);                                            \
    _Pragma("unroll") for (int ai = 0; ai < 2; ++ai)                          \
      _Pragma("unroll") for (int ni = 0; ni < 4; ++ni)                        \
        _Pragma("unroll") for (int kk = 0; kk < 2; ++kk)                      \
          acc[2 * (q) + ai][ni] =                                             \
              mfma16<DT>(afr[ai][kk], bfr[ni][kk], acc[2 * (q) + ai][ni]);    \
    __builtin_amdgcn_s_setprio(0);                                            \
    if (VM) { asm volatile("s_waitcnt vmcnt(6)" ::: "memory"); }              \
    __builtin_amdgcn_s_barrier();                                             \
  }

  sB(0, 0, 0); sB(0, 1, 0);
  sA(0, 0, 0); sA(0, 1, 0);
  sB(1, 0, 64); sB(1, 1, 64);
  sA(1, 0, 64);
  asm volatile("s_waitcnt vmcnt(6)" ::: "memory");
  __builtin_amdgcn_s_barrier();

  for (int i = 0; i < NI; ++i) {
    const int a1c = (2 * i + 1) << 6;
    const int c0  = ((2 * i + 2 < NT) ? 2 * i + 2 : NT - 1) << 6;
    const int c1  = ((2 * i + 3 < NT) ? 2 * i + 3 : NT - 1) << 6;
    PHASE(0, 0, true,  sA(1, 1, a1c), false)
    PHASE(0, 1, false, sB(0, 0, c0), false)
    PHASE(0, 2, false, sB(0, 1, c0), false)
    PHASE(0, 3, false, sA(0, 0, c0), true)
    PHASE(1, 0, true,  sA(0, 1, c0), false)
    PHASE(1, 1, false, sB(1, 0, c1), false)
    PHASE(1, 2, false, sB(1, 1, c1), false)
    PHASE(1, 3, false, sA(1, 0, c1), true)
  }
#undef PHASE
#undef LOADB

  const int rg = (lane >> 4) * 4;
  #pragma unroll
  for (int ni = 0; ni < 4; ++ni) {
    const int gn = n0 + wn * 64 + ni * 16 + fr;
    const float bvl = bias[gn];
    #pragma unroll
    for (int mi = 0; mi < 8; ++mi) {
      const int gmB = m0 + wm * 128 + mi * 16 + rg;
      f32x4 v = acc[mi][ni];
      if (OM == 0) {
        float* Cf = (float*)Cp;
        #pragma unroll
        for (int r = 0; r < 4; ++r)
          Cf[(long)(gmB + r) * LDC + gn] = v[r] + bvl;
      } else if (OM == 2) {   // fp16 row-major
        unsigned short* Ch = (unsigned short*)Cp;
        #pragma unroll
        for (int r = 0; r < 4; ++r)
          Ch[(long)(gmB + r) * LDC + gn] =
              __builtin_bit_cast(unsigned short, (_Float16)(v[r] + bvl));
      } else {                // OM == 1: vT scatter (bf16)
        const int b = gmB >> 8, s = gmB & 255, h = gn >> 8, ii = gn & 255;
        u16x4 o;
        #pragma unroll
        for (int r = 0; r < 4; ++r) o[r] = f2bf(v[r] + bvl);
        *(u16x4*)&((unsigned short*)Cp)[((long)((b * 8 + h) * 256 + ii) << 8) + s] = o;
      }
    }
  }
}

// ---------------- 128x128 NT GEMM (m97 structure) — aggregation ----------------
template<int MODE, int OM, bool BATCHED>
__global__ __launch_bounds__(256)
void fgemm(const unsigned short* __restrict__ A, const unsigned short* __restrict__ B,
           const float* __restrict__ bias, void* __restrict__ C,
           int lda, int ldb, int ldc, int KT)
{
  __shared__ __align__(16) unsigned short lA[2 * 128 * 32];
  __shared__ __align__(16) unsigned short lB[2 * 128 * 32];

  const int tid  = threadIdx.x;
  const int lane = tid & 63;
  const int wid  = tid >> 6;
  const int wr   = wid >> 1;
  const int wc   = wid & 1;

  const int z  = BATCHED ? blockIdx.z : 0;
  const int m0 = blockIdx.y * 128;
  const int n0 = blockIdx.x * 128;

  long aBase = (long)m0 * lda;
  long bBase = (long)n0 * ldb;
  if (BATCHED) {
    aBase += (long)z * 256 * lda;
    bBase += (long)z * 256 * ldb;
  }

  const int ar0 = tid >> 2, ac0 = (tid & 3) * 8;
  const int ar1 = ar0 + 64, ac1 = ac0;

  const unsigned short* pa0 = A + aBase + (long)ar0 * lda + ac0;
  const unsigned short* pa1 = A + aBase + (long)ar1 * lda + ac1;
  const unsigned short* pb0 = B + bBase + (long)ar0 * ldb + ac0;
  const unsigned short* pb1 = B + bBase + (long)ar1 * ldb + ac1;

  constexpr int SUBOFF = (MODE == 0) ? 2048 : 32;
  constexpr int KSTEP  = (MODE == 0) ? 32 : 64;

  f32x4 acc[4][4];
  #pragma unroll
  for (int i = 0; i < 4; ++i)
    #pragma unroll
    for (int j = 0; j < 4; ++j)
      acc[i][j] = (f32x4)(0.0f);

  const int fr   = lane & 15;
  const int krow = (lane >> 4) * 8;

  for (int kt = 0; kt < KT; kt += KSTEP) {
    gload16(pa0 + kt,          lA + tid * 8);
    gload16(pa1 + kt,          lA + (tid + 256) * 8);
    gload16(pa0 + kt + SUBOFF, lA + 4096 + tid * 8);
    gload16(pa1 + kt + SUBOFF, lA + 4096 + (tid + 256) * 8);
    gload16(pb0 + kt,          lB + tid * 8);
    gload16(pb1 + kt,          lB + (tid + 256) * 8);
    gload16(pb0 + kt + SUBOFF, lB + 4096 + tid * 8);
    gload16(pb1 + kt + SUBOFF, lB + 4096 + (tid + 256) * 8);
    __syncthreads();

    s16x8 a0[4], a1[4], b0[4], b1[4];
    #pragma unroll
    for (int i = 0; i < 4; ++i) {
      const int r = (wr * 64 + i * 16 + fr) * 32 + krow;
      a0[i] = *(const s16x8*)&lA[r];
      a1[i] = *(const s16x8*)&lA[4096 + r];
    }
    #pragma unroll
    for (int j = 0; j < 4; ++j) {
      const int r = (wc * 64 + j * 16 + fr) * 32 + krow;
      b0[j] = *(const s16x8*)&lB[r];
      b1[j] = *(const s16x8*)&lB[4096 + r];
    }

    #pragma unroll
    for (int i = 0; i < 4; ++i)
      #pragma unroll
      for (int j = 0; j < 4; ++j) {
        if (MODE == 0) {
          acc[i][j] = __builtin_amdgcn_mfma_f32_16x16x32_bf16(a1[i], b0[j], acc[i][j], 0, 0, 0);
          acc[i][j] = __builtin_amdgcn_mfma_f32_16x16x32_bf16(a0[i], b1[j], acc[i][j], 0, 0, 0);
          acc[i][j] = __builtin_amdgcn_mfma_f32_16x16x32_bf16(a0[i], b0[j], acc[i][j], 0, 0, 0);
        } else {
          acc[i][j] = __builtin_amdgcn_mfma_f32_16x16x32_bf16(a0[i], b0[j], acc[i][j], 0, 0, 0);
          acc[i][j] = __builtin_amdgcn_mfma_f32_16x16x32_bf16(a1[i], b1[j], acc[i][j], 0, 0, 0);
        }
      }

    __syncthreads();
  }

  const int rg = (lane >> 4) * 4;
  #pragma unroll
  for (int j = 0; j < 4; ++j) {
    const int gn = n0 + wc * 64 + j * 16 + fr;
    const float bvl = bias ? bias[gn] : 0.0f;
    #pragma unroll
    for (int i = 0; i < 4; ++i) {
      const int gmB = m0 + wr * 64 + i * 16 + rg;
      f32x4 v = acc[i][j];
      if (OM == 0) {
        float* Cf = (float*)C;
        #pragma unroll
        for (int r = 0; r < 4; ++r)
          Cf[(long)(gmB + r) * ldc + gn] = v[r] + bvl;
      } else if (OM == 2) {
        long cb = 0;
        if (BATCHED) cb = (long)(z >> 3) * 256 * ldc + (long)(z & 7) * 256;
        unsigned short* Ch = (unsigned short*)C;
        #pragma unroll
        for (int r = 0; r < 4; ++r)
          Ch[cb + (long)(gmB + r) * ldc + gn] = f2bf(v[r] + bvl);
      } else {
        const int b = gmB >> 8, s = gmB & 255, h = gn >> 8, ii = gn & 255;
        u16x4 o;
        #pragma unroll
        for (int r = 0; r < 4; ++r) o[r] = f2bf(v[r] + bvl);
        *(u16x4*)&((unsigned short*)C)[((long)((b * 8 + h) * 256 + ii) << 8) + s] = o;
      }
    }
  }
}

// ---------------- circular correlation + softmax (fp16 dot2, shifted-Q) ----------------
// one wave per (b,h,l) row; lane owns lags d=4*lane..d+3, e = 2*lane.
//  even D: c_D = sum_v fdot2(K2[v], Q2[v + D/2])         v=0..127
//  odd  D: c_D = sum_v fdot2(K2[v], Q2s[v + (D-1)/2])    Q2s from qs2[i]=q[i+1]
// Fully unrolled t-loop: window copies become SSA renames (no v_mov), all DS
// addresses fold to base + immediate offset (no per-iter address VALU).
__global__ __launch_bounds__(256)
void corr_softmax(const unsigned short* __restrict__ qp,
                  const unsigned short* __restrict__ kp,
                  const float* __restrict__ temp, unsigned short* __restrict__ w)
{
  __shared__ __align__(16) unsigned short qs[4][520];  // q (dup)
  __shared__ __align__(16) unsigned short q2[4][520];  // q shifted by 1 (dup)
  __shared__ __align__(16) unsigned short ks[4][264];  // k
  const int tid  = threadIdx.x;
  const int lane = tid & 63;
  const int wid  = tid >> 6;
  const int row  = blockIdx.x * 4 + wid;       // ((b*8+h)*256+l)
  const int b = row >> 11;
  const int h = (row >> 8) & 7;
  const int l = row & 255;
  const long base = ((long)(b * 256 + l) << 11) + h * 256;

  {
    u16x4 qv = *(const u16x4*)(qp + base + 4 * lane);
    u16x4 kv = *(const u16x4*)(kp + base + 4 * lane);
    const int nxt = __shfl((int)(unsigned int)(unsigned short)qv[0],
                           (lane + 1) & 63, 64);
    u16x4 qsv;
    qsv[0] = qv[1]; qsv[1] = qv[2]; qsv[2] = qv[3];
    qsv[3] = (unsigned short)(unsigned int)nxt;
    *(u16x4*)&qs[wid][4 * lane]       = qv;
    *(u16x4*)&qs[wid][256 + 4 * lane] = qv;
    *(u16x4*)&q2[wid][4 * lane]       = qsv;
    *(u16x4*)&q2[wid][256 + 4 * lane] = qsv;
    *(u16x4*)&ks[wid][4 * lane]       = kv;
  }
  __syncthreads();

  const unsigned short* Q  = &qs[wid][0];
  const unsigned short* Qs = &q2[wid][0];
  const unsigned short* K  = &ks[wid][0];
  const int e = 2 * lane;

  u32x2 A  = *(const u32x2*)&Q[2 * e];
  u32x2 B  = *(const u32x2*)&Q[2 * (e + 2)];
  u32x2 C  = *(const u32x2*)&Q[2 * (e + 4)];
  u32x2 A2 = *(const u32x2*)&Qs[2 * e];
  u32x2 B2 = *(const u32x2*)&Qs[2 * (e + 2)];
  u32x2 C2 = *(const u32x2*)&Qs[2 * (e + 4)];

  float c0 = 0.f, c1 = 0.f, c2 = 0.f, c3 = 0.f;

  #pragma unroll
  for (int t = 0; t < 32; ++t) {
    u32x4 Kw = *(const u32x4*)&K[8 * t];        // K2[4t..4t+3], uniform
    const unsigned int p0 = A[0],  p1 = A[1],  p2 = B[0],  p3 = B[1],  p4 = C[0];
    const unsigned int s0 = A2[0], s1 = A2[1], s2 = B2[0], s3 = B2[1], s4 = C2[0];
    c0 = fdot2u(Kw[0], p0, c0); c2 = fdot2u(Kw[0], p1, c2);
    c1 = fdot2u(Kw[0], s0, c1); c3 = fdot2u(Kw[0], s1, c3);
    c0 = fdot2u(Kw[1], p1, c0); c2 = fdot2u(Kw[1], p2, c2);
    c1 = fdot2u(Kw[1], s1, c1); c3 = fdot2u(Kw[1], s2, c3);
    c0 = fdot2u(Kw[2], p2, c0); c2 = fdot2u(Kw[2], p3, c2);
    c1 = fdot2u(Kw[2], s2, c1); c3 = fdot2u(Kw[2], s3, c3);
    c0 = fdot2u(Kw[3], p3, c0); c2 = fdot2u(Kw[3], p4, c2);
    c1 = fdot2u(Kw[3], s3, c1); c3 = fdot2u(Kw[3], s4, c3);
    A = C;  A2 = C2;
    B  = *(const u32x2*)&Q[2 * (4 * t + e + 6)];
    C  = *(const u32x2*)&Q[2 * (4 * t + e + 8)];
    B2 = *(const u32x2*)&Qs[2 * (4 * t + e + 6)];
    C2 = *(const u32x2*)&Qs[2 * (4 * t + e + 8)];
  }

  const float invT = 1.0f / temp[h];
  float mx = fmaxf(fmaxf(c0, c1), fmaxf(c2, c3));
  #pragma unroll
  for (int off = 32; off >= 1; off >>= 1) mx = fmaxf(mx, __shfl_xor(mx, off, 64));
  const float e0 = __expf((c0 - mx) * invT);
  const float e1 = __expf((c1 - mx) * invT);
  const float e2 = __expf((c2 - mx) * invT);
  const float e3 = __expf((c3 - mx) * invT);
  float sm = e0 + e1 + e2 + e3;
  #pragma unroll
  for (int off = 32; off >= 1; off >>= 1) sm += __shfl_xor(sm, off, 64);
  const float rs = 1.0f / sm;
  u16x4 o;
  o[0] = f2bf(e0 * rs); o[1] = f2bf(e1 * rs); o[2] = f2bf(e2 * rs); o[3] = f2bf(e3 * rs);
  *(u16x4*)(w + (long)row * 256 + 4 * lane) = o;
}

// ---------------- launcher ----------------

extern "C" void kernel_launch(void* const* d_in, const int* in_sizes, int n_in,
                              void* d_out, int out_size, void* d_ws, size_t ws_size,
                              hipStream_t stream) {
  (void)in_sizes; (void)n_in; (void)out_size; (void)ws_size;
  const float* queries = (const float*)d_in[0];
  const float* keys    = (const float*)d_in[1];
  const float* values  = (const float*)d_in[2];
  const float* Wq = (const float*)d_in[3];
  const float* bq = (const float*)d_in[4];
  const float* Wk = (const float*)d_in[5];
  const float* bk = (const float*)d_in[6];
  const float* Wv = (const float*)d_in[7];
  const float* bv = (const float*)d_in[8];
  const float* Wo = (const float*)d_in[9];
  const float* bo = (const float*)d_in[10];
  const float* temp = (const float*)d_in[11];

  // workspace (peak 136 MiB) + d_out as W-pack scratch:
  //  ws[0,32)    extA (f16 queries/keys; then bf16 values)
  //  ws[32,64)   qproj f16 -> vT bf16 (after corr)
  //  ws[64,96)   kproj f16 -> out2 bf16 (after corr)
  //  ws[96,128)  wgt bf16
  //  ws[128,136) Wob bf16
  //  d_out       extW (packed W, 8 MiB) until the final GEMM
  char* ws = (char*)d_ws;
  auto MB = [](size_t m) { return m << 20; };
  unsigned short* extA = (unsigned short*)ws;
  unsigned short* Vb   = (unsigned short*)ws;
  unsigned short* qproj= (unsigned short*)(ws + MB(32));
  unsigned short* vT   = (unsigned short*)(ws + MB(32));
  unsigned short* kproj= (unsigned short*)(ws + MB(64));
  unsigned short* out2 = (unsigned short*)(ws + MB(64));
  unsigned short* wgt  = (unsigned short*)(ws + MB(96));
  unsigned short* Wob  = (unsigned short*)(ws + MB(128));
  unsigned short* extW = (unsigned short*)d_out;

  dim3 blk(256);
  dim3 gBig(32, 8);
  const long nBig = (long)8192 * 2048 / 8;
  const long nW   = (long)2048 * 2048 / 8;

  // ---- Q projection (fp16 in, fp16 out); pack queries + Wq in one launch ----
  pack3<1, 1, 1><<<2048, blk, 0, stream>>>(queries, extA, nBig, Wq, extW, nW,
                                           nullptr, nullptr, 0);
  gemm8p<1, 2><<<gBig, 512, 0, stream>>>(extA, extW, bq, qproj);
  // ---- K projection (fp16 in, fp16 out) ----
  pack3<1, 1, 1><<<2048, blk, 0, stream>>>(keys, extA, nBig, Wk, extW, nW,
                                           nullptr, nullptr, 0);
  gemm8p<1, 2><<<gBig, 512, 0, stream>>>(extA, extW, bk, kproj);
  // ---- correlation + softmax -> bf16 weights ----
  corr_softmax<<<dim3(16384), blk, 0, stream>>>(qproj, kproj, temp, wgt);
  // ---- V projection (bf16) + pack Wv, Wo in the same launch ----
  pack3<0, 0, 0><<<2048, blk, 0, stream>>>(values, Vb, nBig, Wv, extW, nW,
                                           Wo, Wob, nW);
  gemm8p<0, 1><<<gBig, 512, 0, stream>>>(Vb, extW, bv, vT);
  // ---- aggregation: out2[b*256+l][h*256+i] = sum_s wgt[bhl][s]*vT[bhi][s] ----
  fgemm<1, 2, true><<<dim3(2, 2, 256), blk, 0, stream>>>(wgt, vT, nullptr, out2,
                                                         256, 256, 2048, 256);
  // ---- O projection -> d_out (fp32) ----
  gemm8p<0, 0><<<gBig, 512, 0, stream>>>(out2, Wob, bo, (float*)d_out);
}

// Round 12
// 455.282 us; speedup vs baseline: 1.1561x; 1.0015x over previous
//
#include <hip/hip_runtime.h>
#include <stdint.h>

typedef float  f32x4 __attribute__((ext_vector_type(4)));
typedef short  s16x8 __attribute__((ext_vector_type(8)));
typedef _Float16 h16x8 __attribute__((ext_vector_type(8)));
typedef _Float16 h16x2 __attribute__((ext_vector_type(2)));
typedef unsigned short u16x4 __attribute__((ext_vector_type(4)));
typedef unsigned int u32x2 __attribute__((ext_vector_type(2)));
typedef unsigned int u32x4 __attribute__((ext_vector_type(4)));

#define DEV __device__ __forceinline__

DEV unsigned short f2bf(float f) {
  union { float f; unsigned int u; } v; v.f = f;
  unsigned int u = v.u;
  return (unsigned short)((u + 0x7fffu + ((u >> 16) & 1u)) >> 16);
}

typedef const __attribute__((address_space(1))) void* as1cvp;
typedef __attribute__((address_space(3))) void* as3vp;
DEV void gload16(const void* g, void* l) {
  __builtin_amdgcn_global_load_lds((as1cvp)g, (as3vp)l, 16, 0, 0);
}

DEV float fdot2u(unsigned int a, unsigned int b, float c) {
  return __builtin_amdgcn_fdot2(__builtin_bit_cast(h16x2, a),
                                __builtin_bit_cast(h16x2, b), c, false);
}

// ---------------- pack kernel: 3 segments, per-segment dtype ----------------
// MODE 0 = bf16, 1 = fp16. Counts are in groups of 8 elements.
template<int M0, int M1, int M2>
__global__ __launch_bounds__(256)
void pack3(const float* __restrict__ in0, unsigned short* __restrict__ out0, long n0,
           const float* __restrict__ in1, unsigned short* __restrict__ out1, long n1,
           const float* __restrict__ in2, unsigned short* __restrict__ out2, long n2)
{
  const long total = n0 + n1 + n2;
  for (long t = (long)blockIdx.x * 256 + threadIdx.x; t < total;
       t += (long)gridDim.x * 256) {
    const float* src; unsigned short* dst; long i; int mode;
    if (t < n0)           { src = in0; dst = out0; i = t;           mode = M0; }
    else if (t < n0 + n1) { src = in1; dst = out1; i = t - n0;      mode = M1; }
    else                  { src = in2; dst = out2; i = t - n0 - n1; mode = M2; }
    f32x4 x0 = *(const f32x4*)(src + i * 8);
    f32x4 x1 = *(const f32x4*)(src + i * 8 + 4);
    s16x8 h8;
    #pragma unroll
    for (int e = 0; e < 4; ++e) {
      if (mode == 1) {
        h8[e]     = (short)__builtin_bit_cast(unsigned short, (_Float16)x0[e]);
        h8[e + 4] = (short)__builtin_bit_cast(unsigned short, (_Float16)x1[e]);
      } else {
        h8[e]     = (short)f2bf(x0[e]);
        h8[e + 4] = (short)f2bf(x1[e]);
      }
    }
    *(s16x8*)(dst + i * 8) = h8;
  }
}

// ---------------- 256x256 8-phase NT GEMM (bf16 or fp16) ----------------
// Grid (32, 8): bx -> M-block via XCD remap; by -> N-block. K = 2048.
// DT 0: bf16 MFMA; DT 1: fp16 MFMA.
// OM 0: fp32 row-major; OM 1: bf16 scatter vT[((b*8+h)*256+i)*256+s];
// OM 2: fp16 row-major.
template<int DT>
DEV f32x4 mfma16(s16x8 a, s16x8 b, f32x4 c) {
  if constexpr (DT == 0)
    return __builtin_amdgcn_mfma_f32_16x16x32_bf16(a, b, c, 0, 0, 0);
  else
    return __builtin_amdgcn_mfma_f32_16x16x32_f16(
        __builtin_bit_cast(h16x8, a), __builtin_bit_cast(h16x8, b), c, 0, 0, 0);
}

template<int DT, int OM>
__global__ __launch_bounds__(512, 2)
void gemm8p(const unsigned short* __restrict__ Ap, const unsigned short* __restrict__ Bp,
            const float* __restrict__ bias, void* __restrict__ Cp)
{
  constexpr int LD  = 2048;
  constexpr int LDC = 2048;
  constexpr int NT  = 32;
  constexpr int NI  = NT / 2;

  __shared__ __align__(16) unsigned short lds[65536];

  const int tid  = threadIdx.x;
  const int lane = tid & 63;
  const int wid  = tid >> 6;
  const int wm   = wid >> 2;
  const int wn   = wid & 3;
  const int fr   = lane & 15;
  const int ko   = (lane >> 4) * 8;

  const int bx = blockIdx.x;
  const int m0 = (((bx & 7) << 2) + (bx >> 3)) * 256;
  const int n0 = blockIdx.y * 256;

  const int sr  = tid >> 3;
  const int scc = (((tid & 7) ^ (((tid >> 5) & 1) << 2)) << 3);

  auto sA = [&](int d, int u, int col) {
    const unsigned short* s0 = Ap + (long)(m0 + u * 64 + sr) * LD + col + scc;
    const int lb = d * 32768 + u * 4096 + (wid << 9);
    gload16(s0, lds + lb);
    gload16(s0 + 128 * LD, lds + lb + 8192);
  };
  auto sB = [&](int d, int h, int col) {
    const unsigned short* s0 = Bp + (long)(n0 + h * 128 + sr) * LD + col + scc;
    const int lb = d * 32768 + 16384 + h * 8192 + (wid << 9);
    gload16(s0, lds + lb);
    gload16(s0 + 64 * LD, lds + lb + 4096);
  };

  f32x4 acc[8][4];
  #pragma unroll
  for (int i = 0; i < 8; ++i)
    #pragma unroll
    for (int j = 0; j < 4; ++j)
      acc[i][j] = (f32x4)(0.0f);

  s16x8 afr[2][2], bfr[4][2];

#define LOADB(d)                                                              \
  _Pragma("unroll") for (int ni = 0; ni < 4; ++ni)                            \
    _Pragma("unroll") for (int kk = 0; kk < 2; ++kk) {                        \
      const int nr = wn * 64 + ni * 16 + fr;                                  \
      int u = (d) * 32768 + 16384 + (nr >> 7) * 8192 + (nr & 127) * 64        \
              + kk * 32 + ko;                                                 \
      u ^= ((u >> 8) & 1) << 5;                                               \
      bfr[ni][kk] = *(const s16x8*)&lds[u];                                   \
    }

#define PHASE(d, q, DOB, STAGE, VM)                                           \
  {                                                                           \
    if (DOB) { LOADB(d) }                                                     \
    _Pragma("unroll") for (int ai = 0; ai < 2; ++ai)                          \
      _Pragma("unroll") for (int kk = 0; kk < 2; ++kk) {                      \
        int u = (d) * 32768 + wm * 8192 + ((2 * (q) + ai) * 16 + fr) * 64     \
                + kk * 32 + ko;                                               \
        u ^= ((u >> 8) & 1) << 5;                                             \
        afr[ai][kk] = *(const s16x8*)&lds[u];                                 \
      }                                                                       \
    STAGE;                                                                    \
    __builtin_amdgcn_s_barrier();                                             \
    asm volatile("s_waitcnt lgkmcnt(0)" ::: "memory");                        \
    __builtin_amdgcn_sched_barrier(0);                                        \
    __builtin_amdgcn_s_setprio(1);                                            \
    _Pragma("unroll") for (int ai = 0; ai < 2; ++ai)                          \
      _Pragma("unroll") for (int ni = 0; ni < 4; ++ni)                        \
        _Pragma("unroll") for (int kk = 0; kk < 2; ++kk)                      \
          acc[2 * (q) + ai][ni] =                                             \
              mfma16<DT>(afr[ai][kk], bfr[ni][kk], acc[2 * (q) + ai][ni]);    \
    __builtin_amdgcn_s_setprio(0);                                            \
    if (VM) { asm volatile("s_waitcnt vmcnt(6)" ::: "memory"); }              \
    __builtin_amdgcn_s_barrier();                                             \
  }

  sB(0, 0, 0); sB(0, 1, 0);
  sA(0, 0, 0); sA(0, 1, 0);
  sB(1, 0, 64); sB(1, 1, 64);
  sA(1, 0, 64);
  asm volatile("s_waitcnt vmcnt(6)" ::: "memory");
  __builtin_amdgcn_s_barrier();

  for (int i = 0; i < NI; ++i) {
    const int a1c = (2 * i + 1) << 6;
    const int c0  = ((2 * i + 2 < NT) ? 2 * i + 2 : NT - 1) << 6;
    const int c1  = ((2 * i + 3 < NT) ? 2 * i + 3 : NT - 1) << 6;
    PHASE(0, 0, true,  sA(1, 1, a1c), false)
    PHASE(0, 1, false, sB(0, 0, c0), false)
    PHASE(0, 2, false, sB(0, 1, c0), false)
    PHASE(0, 3, false, sA(0, 0, c0), true)
    PHASE(1, 0, true,  sA(0, 1, c0), false)
    PHASE(1, 1, false, sB(1, 0, c1), false)
    PHASE(1, 2, false, sB(1, 1, c1), false)
    PHASE(1, 3, false, sA(1, 0, c1), true)
  }
#undef PHASE
#undef LOADB

  const int rg = (lane >> 4) * 4;
  #pragma unroll
  for (int ni = 0; ni < 4; ++ni) {
    const int gn = n0 + wn * 64 + ni * 16 + fr;
    const float bvl = bias[gn];
    #pragma unroll
    for (int mi = 0; mi < 8; ++mi) {
      const int gmB = m0 + wm * 128 + mi * 16 + rg;
      f32x4 v = acc[mi][ni];
      if (OM == 0) {
        float* Cf = (float*)Cp;
        #pragma unroll
        for (int r = 0; r < 4; ++r)
          Cf[(long)(gmB + r) * LDC + gn] = v[r] + bvl;
      } else if (OM == 2) {   // fp16 row-major
        unsigned short* Ch = (unsigned short*)Cp;
        #pragma unroll
        for (int r = 0; r < 4; ++r)
          Ch[(long)(gmB + r) * LDC + gn] =
              __builtin_bit_cast(unsigned short, (_Float16)(v[r] + bvl));
      } else {                // OM == 1: vT scatter (bf16)
        const int b = gmB >> 8, s = gmB & 255, h = gn >> 8, ii = gn & 255;
        u16x4 o;
        #pragma unroll
        for (int r = 0; r < 4; ++r) o[r] = f2bf(v[r] + bvl);
        *(u16x4*)&((unsigned short*)Cp)[((long)((b * 8 + h) * 256 + ii) << 8) + s] = o;
      }
    }
  }
}

// ---------------- 128x128 NT GEMM (m97 structure) — aggregation ----------------
template<int MODE, int OM, bool BATCHED>
__global__ __launch_bounds__(256)
void fgemm(const unsigned short* __restrict__ A, const unsigned short* __restrict__ B,
           const float* __restrict__ bias, void* __restrict__ C,
           int lda, int ldb, int ldc, int KT)
{
  __shared__ __align__(16) unsigned short lA[2 * 128 * 32];
  __shared__ __align__(16) unsigned short lB[2 * 128 * 32];

  const int tid  = threadIdx.x;
  const int lane = tid & 63;
  const int wid  = tid >> 6;
  const int wr   = wid >> 1;
  const int wc   = wid & 1;

  const int z  = BATCHED ? blockIdx.z : 0;
  const int m0 = blockIdx.y * 128;
  const int n0 = blockIdx.x * 128;

  long aBase = (long)m0 * lda;
  long bBase = (long)n0 * ldb;
  if (BATCHED) {
    aBase += (long)z * 256 * lda;
    bBase += (long)z * 256 * ldb;
  }

  const int ar0 = tid >> 2, ac0 = (tid & 3) * 8;
  const int ar1 = ar0 + 64, ac1 = ac0;

  const unsigned short* pa0 = A + aBase + (long)ar0 * lda + ac0;
  const unsigned short* pa1 = A + aBase + (long)ar1 * lda + ac1;
  const unsigned short* pb0 = B + bBase + (long)ar0 * ldb + ac0;
  const unsigned short* pb1 = B + bBase + (long)ar1 * ldb + ac1;

  constexpr int SUBOFF = (MODE == 0) ? 2048 : 32;
  constexpr int KSTEP  = (MODE == 0) ? 32 : 64;

  f32x4 acc[4][4];
  #pragma unroll
  for (int i = 0; i < 4; ++i)
    #pragma unroll
    for (int j = 0; j < 4; ++j)
      acc[i][j] = (f32x4)(0.0f);

  const int fr   = lane & 15;
  const int krow = (lane >> 4) * 8;

  for (int kt = 0; kt < KT; kt += KSTEP) {
    gload16(pa0 + kt,          lA + tid * 8);
    gload16(pa1 + kt,          lA + (tid + 256) * 8);
    gload16(pa0 + kt + SUBOFF, lA + 4096 + tid * 8);
    gload16(pa1 + kt + SUBOFF, lA + 4096 + (tid + 256) * 8);
    gload16(pb0 + kt,          lB + tid * 8);
    gload16(pb1 + kt,          lB + (tid + 256) * 8);
    gload16(pb0 + kt + SUBOFF, lB + 4096 + tid * 8);
    gload16(pb1 + kt + SUBOFF, lB + 4096 + (tid + 256) * 8);
    __syncthreads();

    s16x8 a0[4], a1[4], b0[4], b1[4];
    #pragma unroll
    for (int i = 0; i < 4; ++i) {
      const int r = (wr * 64 + i * 16 + fr) * 32 + krow;
      a0[i] = *(const s16x8*)&lA[r];
      a1[i] = *(const s16x8*)&lA[4096 + r];
    }
    #pragma unroll
    for (int j = 0; j < 4; ++j) {
      const int r = (wc * 64 + j * 16 + fr) * 32 + krow;
      b0[j] = *(const s16x8*)&lB[r];
      b1[j] = *(const s16x8*)&lB[4096 + r];
    }

    #pragma unroll
    for (int i = 0; i < 4; ++i)
      #pragma unroll
      for (int j = 0; j < 4; ++j) {
        if (MODE == 0) {
          acc[i][j] = __builtin_amdgcn_mfma_f32_16x16x32_bf16(a1[i], b0[j], acc[i][j], 0, 0, 0);
          acc[i][j] = __builtin_amdgcn_mfma_f32_16x16x32_bf16(a0[i], b1[j], acc[i][j], 0, 0, 0);
          acc[i][j] = __builtin_amdgcn_mfma_f32_16x16x32_bf16(a0[i], b0[j], acc[i][j], 0, 0, 0);
        } else {
          acc[i][j] = __builtin_amdgcn_mfma_f32_16x16x32_bf16(a0[i], b0[j], acc[i][j], 0, 0, 0);
          acc[i][j] = __builtin_amdgcn_mfma_f32_16x16x32_bf16(a1[i], b1[j], acc[i][j], 0, 0, 0);
        }
      }

    __syncthreads();
  }

  const int rg = (lane >> 4) * 4;
  #pragma unroll
  for (int j = 0; j < 4; ++j) {
    const int gn = n0 + wc * 64 + j * 16 + fr;
    const float bvl = bias ? bias[gn] : 0.0f;
    #pragma unroll
    for (int i = 0; i < 4; ++i) {
      const int gmB = m0 + wr * 64 + i * 16 + rg;
      f32x4 v = acc[i][j];
      if (OM == 0) {
        float* Cf = (float*)C;
        #pragma unroll
        for (int r = 0; r < 4; ++r)
          Cf[(long)(gmB + r) * ldc + gn] = v[r] + bvl;
      } else if (OM == 2) {
        long cb = 0;
        if (BATCHED) cb = (long)(z >> 3) * 256 * ldc + (long)(z & 7) * 256;
        unsigned short* Ch = (unsigned short*)C;
        #pragma unroll
        for (int r = 0; r < 4; ++r)
          Ch[cb + (long)(gmB + r) * ldc + gn] = f2bf(v[r] + bvl);
      } else {
        const int b = gmB >> 8, s = gmB & 255, h = gn >> 8, ii = gn & 255;
        u16x4 o;
        #pragma unroll
        for (int r = 0; r < 4; ++r) o[r] = f2bf(v[r] + bvl);
        *(u16x4*)&((unsigned short*)C)[((long)((b * 8 + h) * 256 + ii) << 8) + s] = o;
      }
    }
  }
}

// ---------------- circular correlation + softmax (fp16 dot2, shifted-Q) ----------------
// one wave per (b,h,l) row; lane owns lags d=4*lane..d+3, e = 2*lane.
//  even D: c_D = sum_v fdot2(K2[v], Q2[v + D/2])         v=0..127
//  odd  D: c_D = sum_v fdot2(K2[v], Q2s[v + (D-1)/2])    Q2s from qs2[i]=q[i+1]
// Depth-2 software pipeline: 5-pair rolling windows (A..E / A2..E2) per stream,
// loads for iter t+2 issued before iter t's fdot2s; K double-buffered (Knext at
// t=31 reads ks[256..263], in-bounds). Prefetch-dead reads touch uninitialized
// LDS but never feed fdot2.
__global__ __launch_bounds__(256)
void corr_softmax(const unsigned short* __restrict__ qp,
                  const unsigned short* __restrict__ kp,
                  const float* __restrict__ temp, unsigned short* __restrict__ w)
{
  __shared__ __align__(16) unsigned short qs[4][536];  // q (dup [0..511])
  __shared__ __align__(16) unsigned short q2[4][536];  // q shifted by 1 (dup)
  __shared__ __align__(16) unsigned short ks[4][264];  // k
  const int tid  = threadIdx.x;
  const int lane = tid & 63;
  const int wid  = tid >> 6;
  const int row  = blockIdx.x * 4 + wid;       // ((b*8+h)*256+l)
  const int b = row >> 11;
  const int h = (row >> 8) & 7;
  const int l = row & 255;
  const long base = ((long)(b * 256 + l) << 11) + h * 256;

  {
    u16x4 qv = *(const u16x4*)(qp + base + 4 * lane);
    u16x4 kv = *(const u16x4*)(kp + base + 4 * lane);
    const int nxt = __shfl((int)(unsigned int)(unsigned short)qv[0],
                           (lane + 1) & 63, 64);
    u16x4 qsv;
    qsv[0] = qv[1]; qsv[1] = qv[2]; qsv[2] = qv[3];
    qsv[3] = (unsigned short)(unsigned int)nxt;
    *(u16x4*)&qs[wid][4 * lane]       = qv;
    *(u16x4*)&qs[wid][256 + 4 * lane] = qv;
    *(u16x4*)&q2[wid][4 * lane]       = qsv;
    *(u16x4*)&q2[wid][256 + 4 * lane] = qsv;
    *(u16x4*)&ks[wid][4 * lane]       = kv;
  }
  __syncthreads();

  const unsigned short* Q  = &qs[wid][0];
  const unsigned short* Qs = &q2[wid][0];
  const unsigned short* K  = &ks[wid][0];
  const int e = 2 * lane;

  // pair i == u32 at &Q[2*(e+i)]; window at iter t = pairs e+4t .. e+4t+4
  u32x2 A  = *(const u32x2*)&Q[2 * e];
  u32x2 B  = *(const u32x2*)&Q[2 * (e + 2)];
  u32x2 C  = *(const u32x2*)&Q[2 * (e + 4)];
  u32x2 D  = *(const u32x2*)&Q[2 * (e + 6)];
  u32x2 E  = *(const u32x2*)&Q[2 * (e + 8)];
  u32x2 A2 = *(const u32x2*)&Qs[2 * e];
  u32x2 B2 = *(const u32x2*)&Qs[2 * (e + 2)];
  u32x2 C2 = *(const u32x2*)&Qs[2 * (e + 4)];
  u32x2 D2 = *(const u32x2*)&Qs[2 * (e + 6)];
  u32x2 E2 = *(const u32x2*)&Qs[2 * (e + 8)];
  u32x4 Kc = *(const u32x4*)&K[0];

  float c0 = 0.f, c1 = 0.f, c2 = 0.f, c3 = 0.f;

  #pragma unroll
  for (int t = 0; t < 32; ++t) {
    // prefetch: K for t+1, Q/Qs pairs for t+2
    u32x4 Kn = *(const u32x4*)&K[8 * (t + 1)];
    u32x2 F  = *(const u32x2*)&Q[2 * (4 * t + e + 10)];
    u32x2 G  = *(const u32x2*)&Q[2 * (4 * t + e + 12)];
    u32x2 F2 = *(const u32x2*)&Qs[2 * (4 * t + e + 10)];
    u32x2 G2 = *(const u32x2*)&Qs[2 * (4 * t + e + 12)];
    const unsigned int p0 = A[0],  p1 = A[1],  p2 = B[0],  p3 = B[1],  p4 = C[0];
    const unsigned int s0 = A2[0], s1 = A2[1], s2 = B2[0], s3 = B2[1], s4 = C2[0];
    c0 = fdot2u(Kc[0], p0, c0); c2 = fdot2u(Kc[0], p1, c2);
    c1 = fdot2u(Kc[0], s0, c1); c3 = fdot2u(Kc[0], s1, c3);
    c0 = fdot2u(Kc[1], p1, c0); c2 = fdot2u(Kc[1], p2, c2);
    c1 = fdot2u(Kc[1], s1, c1); c3 = fdot2u(Kc[1], s2, c3);
    c0 = fdot2u(Kc[2], p2, c0); c2 = fdot2u(Kc[2], p3, c2);
    c1 = fdot2u(Kc[2], s2, c1); c3 = fdot2u(Kc[2], s3, c3);
    c0 = fdot2u(Kc[3], p3, c0); c2 = fdot2u(Kc[3], p4, c2);
    c1 = fdot2u(Kc[3], s3, c1); c3 = fdot2u(Kc[3], s4, c3);
    A = C;  B = D;  C = E;  D = F;  E = G;
    A2 = C2; B2 = D2; C2 = E2; D2 = F2; E2 = G2;
    Kc = Kn;
  }

  const float invT = 1.0f / temp[h];
  float mx = fmaxf(fmaxf(c0, c1), fmaxf(c2, c3));
  #pragma unroll
  for (int off = 32; off >= 1; off >>= 1) mx = fmaxf(mx, __shfl_xor(mx, off, 64));
  const float e0 = __expf((c0 - mx) * invT);
  const float e1 = __expf((c1 - mx) * invT);
  const float e2 = __expf((c2 - mx) * invT);
  const float e3 = __expf((c3 - mx) * invT);
  float sm = e0 + e1 + e2 + e3;
  #pragma unroll
  for (int off = 32; off >= 1; off >>= 1) sm += __shfl_xor(sm, off, 64);
  const float rs = 1.0f / sm;
  u16x4 o;
  o[0] = f2bf(e0 * rs); o[1] = f2bf(e1 * rs); o[2] = f2bf(e2 * rs); o[3] = f2bf(e3 * rs);
  *(u16x4*)(w + (long)row * 256 + 4 * lane) = o;
}

// ---------------- launcher ----------------

extern "C" void kernel_launch(void* const* d_in, const int* in_sizes, int n_in,
                              void* d_out, int out_size, void* d_ws, size_t ws_size,
                              hipStream_t stream) {
  (void)in_sizes; (void)n_in; (void)out_size; (void)ws_size;
  const float* queries = (const float*)d_in[0];
  const float* keys    = (const float*)d_in[1];
  const float* values  = (const float*)d_in[2];
  const float* Wq = (const float*)d_in[3];
  const float* bq = (const float*)d_in[4];
  const float* Wk = (const float*)d_in[5];
  const float* bk = (const float*)d_in[6];
  const float* Wv = (const float*)d_in[7];
  const float* bv = (const float*)d_in[8];
  const float* Wo = (const float*)d_in[9];
  const float* bo = (const float*)d_in[10];
  const float* temp = (const float*)d_in[11];

  // workspace (peak 136 MiB) + d_out as W-pack scratch:
  //  ws[0,32)    extA (f16 queries/keys; then bf16 values)
  //  ws[32,64)   qproj f16 -> vT bf16 (after corr)
  //  ws[64,96)   kproj f16 -> out2 bf16 (after corr)
  //  ws[96,128)  wgt bf16
  //  ws[128,136) Wob bf16
  //  d_out       extW (packed W, 8 MiB) until the final GEMM
  char* ws = (char*)d_ws;
  auto MB = [](size_t m) { return m << 20; };
  unsigned short* extA = (unsigned short*)ws;
  unsigned short* Vb   = (unsigned short*)ws;
  unsigned short* qproj= (unsigned short*)(ws + MB(32));
  unsigned short* vT   = (unsigned short*)(ws + MB(32));
  unsigned short* kproj= (unsigned short*)(ws + MB(64));
  unsigned short* out2 = (unsigned short*)(ws + MB(64));
  unsigned short* wgt  = (unsigned short*)(ws + MB(96));
  unsigned short* Wob  = (unsigned short*)(ws + MB(128));
  unsigned short* extW = (unsigned short*)d_out;

  dim3 blk(256);
  dim3 gBig(32, 8);
  const long nBig = (long)8192 * 2048 / 8;
  const long nW   = (long)2048 * 2048 / 8;

  // ---- Q projection (fp16 in, fp16 out); pack queries + Wq in one launch ----
  pack3<1, 1, 1><<<2048, blk, 0, stream>>>(queries, extA, nBig, Wq, extW, nW,
                                           nullptr, nullptr, 0);
  gemm8p<1, 2><<<gBig, 512, 0, stream>>>(extA, extW, bq, qproj);
  // ---- K projection (fp16 in, fp16 out) ----
  pack3<1, 1, 1><<<2048, blk, 0, stream>>>(keys, extA, nBig, Wk, extW, nW,
                                           nullptr, nullptr, 0);
  gemm8p<1, 2><<<gBig, 512, 0, stream>>>(extA, extW, bk, kproj);
  // ---- correlation + softmax -> bf16 weights ----
  corr_softmax<<<dim3(16384), blk, 0, stream>>>(qproj, kproj, temp, wgt);
  // ---- V projection (bf16) + pack Wv, Wo in the same launch ----
  pack3<0, 0, 0><<<2048, blk, 0, stream>>>(values, Vb, nBig, Wv, extW, nW,
                                           Wo, Wob, nW);
  gemm8p<0, 1><<<gBig, 512, 0, stream>>>(Vb, extW, bv, vT);
  // ---- aggregation: out2[b*256+l][h*256+i] = sum_s wgt[bhl][s]*vT[bhi][s] ----
  fgemm<1, 2, true><<<dim3(2, 2, 256), blk, 0, stream>>>(wgt, vT, nullptr, out2,
                                                         256, 256, 2048, 256);
  // ---- O projection -> d_out (fp32) ----
  gemm8p<0, 0><<<gBig, 512, 0, stream>>>(out2, Wob, bo, (float*)d_out);
}